// Round 7
// baseline (39674.484 us; speedup 1.0000x reference)
//
#include <hip/hip_runtime.h>
#include <math.h>

typedef unsigned short u16;
typedef __attribute__((ext_vector_type(4))) float f4;

#define BB 32
#define TT 64
#define DD 512
#define G4_ 2048
#define NBLK 256
#define THR 256

__device__ __forceinline__ float sigf(float x) { return 1.0f / (1.0f + expf(-x)); }

// agent-scope (cross-XCD write-through) store for h-state exchange
__device__ __forceinline__ void astore(float* p, float v) {
    __hip_atomic_store(p, v, __ATOMIC_RELAXED, __HIP_MEMORY_SCOPE_AGENT);
}

// ---------------------------------------------------------------------------
// mask dtype classifier: 0=u8(bool), 1=i32, 2=bf16, 3=f32. Deterministic.
// ---------------------------------------------------------------------------
__global__ void k_flag(const unsigned char* __restrict__ m, int* __restrict__ flag) {
    int tid = threadIdx.x;
    int badbyte = 0, nonz_off = 0, evenu16_nz = 0;
    for (int i = tid * 16; i < tid * 16 + 16; i++) {
        unsigned char c = m[i];
        if (c > 1) badbyte = 1;
        if ((i & 3) != 0 && c != 0) nonz_off = 1;
    }
    const u16* mu = (const u16*)m;
    for (int i = tid * 8; i < tid * 8 + 8; i++) {
        if ((i & 1) == 0 && mu[i] != 0) evenu16_nz = 1;
    }
    __shared__ int s_bad, s_noff, s_env;
    if (tid == 0) { s_bad = 0; s_noff = 0; s_env = 0; }
    __syncthreads();
    if (badbyte) atomicOr(&s_bad, 1);
    if (nonz_off) atomicOr(&s_noff, 1);
    if (evenu16_nz) atomicOr(&s_env, 1);
    __syncthreads();
    if (tid == 0) {
        int f;
        if (s_bad) f = s_env ? 2 : 3;
        else       f = s_noff ? 0 : 1;
        *flag = f;
    }
}

// ---------------------------------------------------------------------------
// init: h0hist slot 0 <- hiddens[0]; h1hist slot 1 <- hiddens[1]; zero barrier.
// ---------------------------------------------------------------------------
__global__ void __launch_bounds__(256) k_init3(const float* __restrict__ hid,
                                               float* __restrict__ h0h,
                                               float* __restrict__ h1h,
                                               int* __restrict__ bar) {
    int i = blockIdx.x * 256 + threadIdx.x;   // 0 .. 16383
    h0h[i] = hid[i];                          // slot 0
    h1h[16384 + i] = hid[16384 + i];          // slot 1
    if (i == 0) { bar[0] = 0; bar[1] = 0; }
}

// ---------------------------------------------------------------------------
// gih0[t][b][j] = b_ih0[j] + b_hh0[j] + sum_k embed[tok[b,t],k] * W_ih0[j,k]
// ---------------------------------------------------------------------------
__global__ void __launch_bounds__(256) k_gih0(const int* __restrict__ tokens,
                                              const float* __restrict__ embed,
                                              const float* __restrict__ Wih,
                                              const float* __restrict__ bih,
                                              const float* __restrict__ bhh,
                                              float* __restrict__ gih0) {
    const int tid = threadIdx.x;
    const int d0 = blockIdx.x * 8;
    const int t = blockIdx.y;
    const int b = tid & 31, dd = tid >> 5;
    const int d = d0 + dd;
    __shared__ float xs[32 * 257];
    __shared__ int toks[32];
    if (tid < 32) toks[tid] = tokens[tid * TT + t];
    float acc[4];
#pragma unroll
    for (int g = 0; g < 4; g++) { int j = g * 512 + d; acc[g] = bih[j] + bhh[j]; }
    __syncthreads();
    for (int c = 0; c < 2; c++) {
        for (int idx = tid; idx < 32 * 64; idx += 256) {
            int b2 = idx >> 6, k4 = idx & 63;
            f4 v = *(const f4*)&embed[(size_t)toks[b2] * 512 + c * 256 + k4 * 4];
            float* dst = &xs[b2 * 257 + k4 * 4];
            dst[0] = v[0]; dst[1] = v[1]; dst[2] = v[2]; dst[3] = v[3];
        }
        __syncthreads();
        for (int k8 = 0; k8 < 32; k8++) {
            float w[4][8];
#pragma unroll
            for (int g = 0; g < 4; g++) {
                const f4* wp = (const f4*)&Wih[(size_t)(g * 512 + d) * 512 + c * 256 + k8 * 8];
                f4 wa = wp[0], wb = wp[1];
#pragma unroll
                for (int kk = 0; kk < 4; kk++) { w[g][kk] = wa[kk]; w[g][4 + kk] = wb[kk]; }
            }
#pragma unroll
            for (int kk = 0; kk < 8; kk++) {
                float xv = xs[b * 257 + k8 * 8 + kk];
#pragma unroll
                for (int g = 0; g < 4; g++) acc[g] += xv * w[g][kk];
            }
        }
        __syncthreads();
    }
    float* grow = gih0 + ((size_t)(t * 32 + b)) * 2048;
#pragma unroll
    for (int g = 0; g < 4; g++) grow[g * 512 + d] = acc[g];
}

// ---------------------------------------------------------------------------
// Persistent recurrence, fresh-slot exchange. 65 phases; phase k:
//   blocks [0,128):   stepA(t=k)   [k<64]: reads h0hist[k], writes slot k+1
//   blocks [128,256): stepB(t=k-1) [k>=1]: reads h20hist[k],h1hist[k], writes k+1
// h-state WRITES: agent-scope atomic stores (write-through to MALL).
// h-state READS: plain f4 loads — safe because slot k+1 addresses are FRESH
// (never in any L2), so a clean miss fetches the written-through value.
// Weights stay plain & L2-resident for the whole kernel. Barrier as R5.
// ---------------------------------------------------------------------------
__global__ void __launch_bounds__(256, 1) k_persist2(
    const float* __restrict__ gih0,
    const float* __restrict__ Whh0,
    const float* __restrict__ Wih1,
    const float* __restrict__ Whh1,
    const float* __restrict__ bih1,
    const float* __restrict__ bhh1,
    const float* __restrict__ cells,
    float* __restrict__ h0h,    // [65][16384]
    float* __restrict__ h20h,   // [65][16384]
    float* __restrict__ h1h,    // [66][16384]
    float* __restrict__ H2,     // [64][16384]
    int* __restrict__ bar)      // [0]=counter [1]=generation
{
    const int blk = blockIdx.x, tid = threadIdx.x;
    const bool isA = (blk < 128);
    const int d0 = (isA ? blk : blk - 128) * 4;
    const int b = tid & 31, u = tid >> 5;

    __shared__ float xs[32][257];
    __shared__ float gbuf[16][33];
    __shared__ float bb1[16];
    __shared__ float clds[128];

    if (tid < 128) {
        int bb = tid & 31, dd = tid >> 5;
        clds[tid] = isA ? cells[bb * 512 + d0 + dd]
                        : cells[16384 + bb * 512 + d0 + dd];
    }
    if (!isA && tid < 16) {
        int j = (tid >> 2) * 512 + d0 + (tid & 3);
        bb1[tid] = bih1[j] + bhh1[j];
    }
    __syncthreads();

    const int m0 = u * 2, m1 = u * 2 + 1;
    const int j0 = (m0 >> 2) * 512 + d0 + (m0 & 3);
    const int j1 = (m1 >> 2) * 512 + d0 + (m1 & 3);
    const float* WA0 = Whh0 + (size_t)j0 * 512;
    const float* WA1 = Whh0 + (size_t)j1 * 512;
    const float* WI0 = Wih1 + (size_t)j0 * 512;
    const float* WI1 = Wih1 + (size_t)j1 * 512;
    const float* WH0 = Whh1 + (size_t)j0 * 512;
    const float* WH1 = Whh1 + (size_t)j1 * 512;

    for (int k = 0; k <= 64; k++) {

        if (isA && k < 64) {                            // ---- stepA (t = k)
            float a0 = gih0[(size_t)k * 65536 + b * 2048 + j0];
            float a1 = gih0[(size_t)k * 65536 + b * 2048 + j1];
            const float* hr = h0h + (size_t)k * 16384;
            for (int c = 0; c < 2; c++) {
                __syncthreads();
                for (int i = tid; i < 2048; i += THR) {
                    int b2 = i >> 6, k4 = i & 63;
                    *(f4*)&xs[b2][k4 * 4] = *(const f4*)&hr[b2 * 512 + c * 256 + k4 * 4];
                }
                __syncthreads();
                const float* w0p = WA0 + c * 256;
                const float* w1p = WA1 + c * 256;
                for (int k4 = 0; k4 < 64; k4++) {
                    f4 x = *(const f4*)&xs[b][k4 * 4];
                    f4 w0 = *(const f4*)&w0p[k4 * 4];
                    f4 w1 = *(const f4*)&w1p[k4 * 4];
                    a0 += x[0] * w0[0]; a0 += x[1] * w0[1]; a0 += x[2] * w0[2]; a0 += x[3] * w0[3];
                    a1 += x[0] * w1[0]; a1 += x[1] * w1[1]; a1 += x[2] * w1[2]; a1 += x[3] * w1[3];
                }
            }
            gbuf[m0][b] = a0; gbuf[m1][b] = a1;
            __syncthreads();
            if (tid < 128) {
                int bb = tid & 31, dd = tid >> 5;
                float gi = gbuf[0 + dd][bb], gf = gbuf[4 + dd][bb];
                float gg = gbuf[8 + dd][bb], go = gbuf[12 + dd][bb];
                float c2 = sigf(gf) * clds[tid] + sigf(gi) * tanhf(gg);
                float h2 = sigf(go) * tanhf(c2);
                astore(&h0h[(size_t)(k + 1) * 16384 + bb * 512 + d0 + dd], c2);   // faithful bug
                astore(&h20h[(size_t)(k + 1) * 16384 + bb * 512 + d0 + dd], h2);
            }
        }

        if (!isA && k >= 1) {                           // ---- stepB (t = k-1)
            float a0 = bb1[m0], a1 = bb1[m1];
            for (int c = 0; c < 4; c++) {
                const float* srcb = (c < 2) ? (h20h + (size_t)k * 16384)
                                            : (h1h + (size_t)k * 16384);
                const int off = (c & 1) * 256;
                const float* w0p = ((c < 2) ? WI0 : WH0) + off;
                const float* w1p = ((c < 2) ? WI1 : WH1) + off;
                __syncthreads();
                for (int i = tid; i < 2048; i += THR) {
                    int b2 = i >> 6, k4 = i & 63;
                    *(f4*)&xs[b2][k4 * 4] = *(const f4*)&srcb[b2 * 512 + off + k4 * 4];
                }
                __syncthreads();
                for (int k4 = 0; k4 < 64; k4++) {
                    f4 x = *(const f4*)&xs[b][k4 * 4];
                    f4 w0 = *(const f4*)&w0p[k4 * 4];
                    f4 w1 = *(const f4*)&w1p[k4 * 4];
                    a0 += x[0] * w0[0]; a0 += x[1] * w0[1]; a0 += x[2] * w0[2]; a0 += x[3] * w0[3];
                    a1 += x[0] * w1[0]; a1 += x[1] * w1[1]; a1 += x[2] * w1[2]; a1 += x[3] * w1[3];
                }
            }
            gbuf[m0][b] = a0; gbuf[m1][b] = a1;
            __syncthreads();
            if (tid < 128) {
                int bb = tid & 31, dd = tid >> 5;
                float gi = gbuf[0 + dd][bb], gf = gbuf[4 + dd][bb];
                float gg = gbuf[8 + dd][bb], go = gbuf[12 + dd][bb];
                float c2 = sigf(gf) * clds[tid] + sigf(gi) * tanhf(gg);
                float h2 = sigf(go) * tanhf(c2);
                astore(&h1h[(size_t)(k + 1) * 16384 + bb * 512 + d0 + dd], c2);   // faithful bug
                H2[(size_t)(k - 1) * 16384 + bb * 512 + d0 + dd] = h2;
            }
        }

        if (k < 64) {                                   // ---- device barrier
            __threadfence();
            __syncthreads();
            if (tid == 0) {
                int old = __hip_atomic_fetch_add(&bar[0], 1, __ATOMIC_ACQ_REL,
                                                 __HIP_MEMORY_SCOPE_AGENT);
                if (old == NBLK - 1) {
                    __hip_atomic_store(&bar[0], 0, __ATOMIC_RELAXED, __HIP_MEMORY_SCOPE_AGENT);
                    __hip_atomic_store(&bar[1], k + 1, __ATOMIC_RELEASE, __HIP_MEMORY_SCOPE_AGENT);
                } else {
                    int spins = 0;
                    while (__hip_atomic_load(&bar[1], __ATOMIC_ACQUIRE,
                                             __HIP_MEMORY_SCOPE_AGENT) < k + 1) {
                        if (++spins > (1 << 20)) break;   // safety valve
                        __builtin_amdgcn_s_sleep(1);
                    }
                }
            }
            __syncthreads();
            __threadfence();
        }
    }
}

// ---------------------------------------------------------------------------
// XQ[t,b,:] = H2[t,b,:] @ W_in^T + b_in
// ---------------------------------------------------------------------------
__global__ void __launch_bounds__(256) k_x(const float* __restrict__ H2,
                                           const float* __restrict__ Win,
                                           const float* __restrict__ bin,
                                           float* __restrict__ XQ) {
    const int tid = threadIdx.x;
    const int j0 = blockIdx.x * 32;
    const int t = blockIdx.y;
    const int b = tid & 31, jj = tid >> 5;
    __shared__ float xs[32 * 257];
    float acc[4];
#pragma unroll
    for (int r = 0; r < 4; r++) acc[r] = bin[j0 + jj * 4 + r];
    const float* H2t = H2 + (size_t)t * 32 * 512;
    for (int c = 0; c < 2; c++) {
        for (int idx = tid; idx < 32 * 64; idx += 256) {
            int b2 = idx >> 6, k4 = idx & 63;
            f4 v = *(const f4*)&H2t[b2 * 512 + c * 256 + k4 * 4];
            float* dst = &xs[b2 * 257 + k4 * 4];
            dst[0] = v[0]; dst[1] = v[1]; dst[2] = v[2]; dst[3] = v[3];
        }
        __syncthreads();
        for (int k8 = 0; k8 < 32; k8++) {
            float w[4][8];
#pragma unroll
            for (int r = 0; r < 4; r++) {
                const f4* wp = (const f4*)&Win[(size_t)(j0 + jj * 4 + r) * 512 + c * 256 + k8 * 8];
                f4 wa = wp[0], wb = wp[1];
#pragma unroll
                for (int kk = 0; kk < 4; kk++) { w[r][kk] = wa[kk]; w[r][4 + kk] = wb[kk]; }
            }
#pragma unroll
            for (int kk = 0; kk < 8; kk++) {
                float xv = xs[b * 257 + k8 * 8 + kk];
#pragma unroll
                for (int r = 0; r < 4; r++) acc[r] += xv * w[r][kk];
            }
        }
        __syncthreads();
    }
    float* xrow = XQ + ((size_t)(t * 32 + b)) * 1024;
#pragma unroll
    for (int r = 0; r < 4; r++) xrow[j0 + jj * 4 + r] = acc[r];
}

// ---------------------------------------------------------------------------
// attention per (t,b): e = enc . xq, masked softmax, ctx = attn . enc
// ---------------------------------------------------------------------------
__global__ void __launch_bounds__(256) k_att(const float* __restrict__ XQ,
                                             const float* __restrict__ enc,
                                             const unsigned char* __restrict__ mask,
                                             const int* __restrict__ flag,
                                             float* __restrict__ CTX) {
    const int tid = threadIdx.x;
    const int b = blockIdx.x, t = blockIdx.y;
    __shared__ float xq[1024];
    __shared__ float ered[256];
    __shared__ float attn[128];
    __shared__ float red2[8];
    {
        f4 v = *(const f4*)&XQ[((size_t)(t * 32 + b)) * 1024 + tid * 4];
        float* dst = &xq[tid * 4];
        dst[0] = v[0]; dst[1] = v[1]; dst[2] = v[2]; dst[3] = v[3];
    }
    __syncthreads();
    const int s = tid >> 1, hh = tid & 1;
    float part = 0.f;
    const float* erow = enc + ((size_t)(b * 128 + s)) * 1024 + hh * 512;
    const float* xqh = &xq[hh * 512];
    for (int k4 = 0; k4 < 128; k4++) {
        f4 u = *(const f4*)&erow[k4 * 4];
#pragma unroll
        for (int kk = 0; kk < 4; kk++) part += u[kk] * xqh[k4 * 4 + kk];
    }
    ered[tid] = part;
    __syncthreads();
    float e = -INFINITY;
    if (tid < 128) {
        e = ered[2 * tid] + ered[2 * tid + 1];
        int f = *flag;
        bool msk;
        if (f == 0)      msk = mask[b * 128 + tid] != 0;
        else if (f == 1) msk = ((const int*)mask)[b * 128 + tid] != 0;
        else if (f == 2) msk = ((const u16*)mask)[b * 128 + tid] != 0;
        else             msk = ((const unsigned int*)mask)[b * 128 + tid] != 0;
        if (msk) e = -1e9f;
    }
    float v = e;
#pragma unroll
    for (int off = 32; off >= 1; off >>= 1) v = fmaxf(v, __shfl_xor(v, off));
    const int wave = tid >> 6;
    if ((tid & 63) == 0) red2[wave] = v;
    __syncthreads();
    float m = fmaxf(fmaxf(red2[0], red2[1]), fmaxf(red2[2], red2[3]));
    float p = (tid < 128) ? expf(e - m) : 0.f;
    float su = p;
#pragma unroll
    for (int off = 32; off >= 1; off >>= 1) su += __shfl_xor(su, off);
    __syncthreads();
    if ((tid & 63) == 0) red2[4 + wave] = su;
    __syncthreads();
    float S = (red2[4] + red2[5]) + (red2[6] + red2[7]);
    if (tid < 128) attn[tid] = p / S;
    __syncthreads();
    float c0 = 0, c1 = 0, c2 = 0, c3 = 0;
    const float* eb = enc + ((size_t)b * 128) * 1024 + tid * 4;
    for (int s2 = 0; s2 < 128; s2++) {
        float a = attn[s2];
        f4 u = *(const f4*)&eb[(size_t)s2 * 1024];
        c0 += a * u[0]; c1 += a * u[1]; c2 += a * u[2]; c3 += a * u[3];
    }
    float* crow = CTX + ((size_t)(t * 32 + b)) * 1024 + tid * 4;
    crow[0] = c0; crow[1] = c1; crow[2] = c2; crow[3] = c3;
}

// ---------------------------------------------------------------------------
// out[t,b,:] = tanh([ctx, s] @ W_out^T + b_out)  -> f32 d_out
// ---------------------------------------------------------------------------
__global__ void __launch_bounds__(256) k_out(const float* __restrict__ CTX,
                                             const float* __restrict__ H2,
                                             const float* __restrict__ Wout,
                                             const float* __restrict__ bout,
                                             float* __restrict__ out) {
    const int tid = threadIdx.x;
    const int j0 = blockIdx.x * 32;
    const int t = blockIdx.y;
    const int b = tid & 31, jj = tid >> 5;
    __shared__ float xs[32 * 257];
    float acc[4];
#pragma unroll
    for (int r = 0; r < 4; r++) acc[r] = bout[j0 + jj * 4 + r];
    const float* Ct = CTX + (size_t)t * 32 * 1024;
    const float* Ht = H2 + (size_t)t * 32 * 512;
    for (int c = 0; c < 6; c++) {
        for (int idx = tid; idx < 32 * 64; idx += 256) {
            int b2 = idx >> 6, k4 = idx & 63;
            const float* src = (c < 4) ? &Ct[b2 * 1024 + c * 256] : &Ht[b2 * 512 + (c - 4) * 256];
            f4 v = *(const f4*)&src[k4 * 4];
            float* dst = &xs[b2 * 257 + k4 * 4];
            dst[0] = v[0]; dst[1] = v[1]; dst[2] = v[2]; dst[3] = v[3];
        }
        __syncthreads();
        for (int k8 = 0; k8 < 32; k8++) {
            float w[4][8];
#pragma unroll
            for (int r = 0; r < 4; r++) {
                const f4* wp = (const f4*)&Wout[(size_t)(j0 + jj * 4 + r) * 1536 + c * 256 + k8 * 8];
                f4 wa = wp[0], wb = wp[1];
#pragma unroll
                for (int kk = 0; kk < 4; kk++) { w[r][kk] = wa[kk]; w[r][4 + kk] = wb[kk]; }
            }
#pragma unroll
            for (int kk = 0; kk < 8; kk++) {
                float xv = xs[b * 257 + k8 * 8 + kk];
#pragma unroll
                for (int r = 0; r < 4; r++) acc[r] += xv * w[r][kk];
            }
        }
        __syncthreads();
    }
    float* orow = out + ((size_t)(t * 32 + b)) * 512;
#pragma unroll
    for (int r = 0; r < 4; r++) orow[j0 + jj * 4 + r] = tanhf(acc[r]);
}

// ---------------------------------------------------------------------------
extern "C" void kernel_launch(void* const* d_in, const int* in_sizes, int n_in,
                              void* d_out, int out_size, void* d_ws, size_t ws_size,
                              hipStream_t stream) {
    const int* tokens   = (const int*)d_in[0];
    const float* enc    = (const float*)d_in[1];
    const float* hidden = (const float*)d_in[2];
    const float* cells  = (const float*)d_in[3];
    const unsigned char* mask = (const unsigned char*)d_in[4];
    const float* embed  = (const float*)d_in[5];
    const float* W_ih   = (const float*)d_in[6];
    const float* W_hh   = (const float*)d_in[7];
    const float* b_ih   = (const float*)d_in[8];
    const float* b_hh   = (const float*)d_in[9];
    const float* W_in   = (const float*)d_in[10];
    const float* b_in   = (const float*)d_in[11];
    const float* W_out  = (const float*)d_in[12];
    const float* b_out  = (const float*)d_in[13];
    float* out = (float*)d_out;

    float* ws = (float*)d_ws;
    float* gih0 = ws;                              // 4,194,304 (reused for XQ/CTX later)
    float* h0h  = ws + 4194304;                    // 65*16384 = 1,064,960
    float* h20h = ws + 5259264;                    // 1,064,960
    float* h1h  = ws + 6324224;                    // 66*16384 = 1,081,344
    float* H2   = ws + 7405568;                    // 1,048,576
    int*   flag = (int*)(ws + 8454144);
    int*   bar  = (int*)(ws + 8454148);
    float* XQ   = ws;                              // reuse gih0 region (dead after persist)
    float* CTX  = ws + 2097152;

    const float* Whh0 = W_hh;
    const float* Wih1 = W_ih + (size_t)G4_ * DD;
    const float* Whh1 = W_hh + (size_t)G4_ * DD;
    const float* bih1 = b_ih + G4_;
    const float* bhh1 = b_hh + G4_;

    k_flag<<<1, 256, 0, stream>>>(mask, flag);
    k_init3<<<64, 256, 0, stream>>>(hidden, h0h, h1h, bar);
    k_gih0<<<dim3(64, 64), 256, 0, stream>>>(tokens, embed, W_ih, b_ih, b_hh, gih0);

    k_persist2<<<NBLK, THR, 0, stream>>>(gih0, Whh0, Wih1, Whh1, bih1, bhh1, cells,
                                         h0h, h20h, h1h, H2, bar);

    k_x<<<dim3(32, 64), 256, 0, stream>>>(H2, W_in, b_in, XQ);
    k_att<<<dim3(32, 64), 256, 0, stream>>>(XQ, enc, mask, flag, CTX);
    k_out<<<dim3(16, 64), 256, 0, stream>>>(CTX, H2, W_out, b_out, out);
}

// Round 8
// 10368.784 us; speedup vs baseline: 3.8263x; 3.8263x over previous
//
#include <hip/hip_runtime.h>
#include <math.h>

typedef unsigned short u16;
typedef __attribute__((ext_vector_type(4))) float f4;

#define BB 32
#define TT 64
#define DD 512
#define G4_ 2048

__device__ __forceinline__ float sigf(float x) { return 1.0f / (1.0f + expf(-x)); }

// ---------------------------------------------------------------------------
// mask dtype classifier: 0=u8(bool), 1=i32, 2=bf16, 3=f32. Deterministic.
// ---------------------------------------------------------------------------
__global__ void k_flag(const unsigned char* __restrict__ m, int* __restrict__ flag) {
    int tid = threadIdx.x;
    int badbyte = 0, nonz_off = 0, evenu16_nz = 0;
    for (int i = tid * 16; i < tid * 16 + 16; i++) {
        unsigned char c = m[i];
        if (c > 1) badbyte = 1;
        if ((i & 3) != 0 && c != 0) nonz_off = 1;
    }
    const u16* mu = (const u16*)m;
    for (int i = tid * 8; i < tid * 8 + 8; i++) {
        if ((i & 1) == 0 && mu[i] != 0) evenu16_nz = 1;
    }
    __shared__ int s_bad, s_noff, s_env;
    if (tid == 0) { s_bad = 0; s_noff = 0; s_env = 0; }
    __syncthreads();
    if (badbyte) atomicOr(&s_bad, 1);
    if (nonz_off) atomicOr(&s_noff, 1);
    if (evenu16_nz) atomicOr(&s_env, 1);
    __syncthreads();
    if (tid == 0) {
        int f;
        if (s_bad) f = s_env ? 2 : 3;
        else       f = s_noff ? 0 : 1;
        *flag = f;
    }
}

// ---------------------------------------------------------------------------
// init: copy initial h-states into both parity buffers.
// ---------------------------------------------------------------------------
__global__ void __launch_bounds__(256) k_init2(const float* __restrict__ hid,
                                               float* __restrict__ h0s,
                                               float* __restrict__ h1s) {
    int i = blockIdx.x * 256 + threadIdx.x;   // 0 .. 16383
    float v0 = hid[i], v1 = hid[16384 + i];
    h0s[i] = v0; h0s[16384 + i] = v0;
    h1s[i] = v1; h1s[16384 + i] = v1;
}

// ---------------------------------------------------------------------------
// gih0[t][b][j] = b_ih0[j] + b_hh0[j] + sum_k embed[tok[b,t],k] * W_ih0[j,k]
// ---------------------------------------------------------------------------
__global__ void __launch_bounds__(256) k_gih0(const int* __restrict__ tokens,
                                              const float* __restrict__ embed,
                                              const float* __restrict__ Wih,
                                              const float* __restrict__ bih,
                                              const float* __restrict__ bhh,
                                              float* __restrict__ gih0) {
    const int tid = threadIdx.x;
    const int d0 = blockIdx.x * 8;
    const int t = blockIdx.y;
    const int b = tid & 31, dd = tid >> 5;
    const int d = d0 + dd;
    __shared__ float xs[32 * 257];
    __shared__ int toks[32];
    if (tid < 32) toks[tid] = tokens[tid * TT + t];
    float acc[4];
#pragma unroll
    for (int g = 0; g < 4; g++) { int j = g * 512 + d; acc[g] = bih[j] + bhh[j]; }
    __syncthreads();
    for (int c = 0; c < 2; c++) {
        for (int idx = tid; idx < 32 * 64; idx += 256) {
            int b2 = idx >> 6, k4 = idx & 63;
            f4 v = *(const f4*)&embed[(size_t)toks[b2] * 512 + c * 256 + k4 * 4];
            float* dst = &xs[b2 * 257 + k4 * 4];
            dst[0] = v[0]; dst[1] = v[1]; dst[2] = v[2]; dst[3] = v[3];
        }
        __syncthreads();
        for (int k8 = 0; k8 < 32; k8++) {
            float w[4][8];
#pragma unroll
            for (int g = 0; g < 4; g++) {
                const f4* wp = (const f4*)&Wih[(size_t)(g * 512 + d) * 512 + c * 256 + k8 * 8];
                f4 wa = wp[0], wb = wp[1];
#pragma unroll
                for (int kk = 0; kk < 4; kk++) { w[g][kk] = wa[kk]; w[g][4 + kk] = wb[kk]; }
            }
#pragma unroll
            for (int kk = 0; kk < 8; kk++) {
                float xv = xs[b * 257 + k8 * 8 + kk];
#pragma unroll
                for (int g = 0; g < 4; g++) acc[g] += xv * w[g][kk];
            }
        }
        __syncthreads();
    }
    float* grow = gih0 + ((size_t)(t * 32 + b)) * 2048;
#pragma unroll
    for (int g = 0; g < 4; g++) grow[g * 512 + d] = acc[g];
}

// ---------------------------------------------------------------------------
// Fused phase kernel, launched for k = 0..67. Stream order = grid sync.
//  blk 0..255   : stepA (t=k,   k<=63)  gates = gih0 + h0 @ Whh0^T
//  blk 256..511 : stepB (t=k-1, 1<=k<=64) gates = h20@Wih1^T + h1@Whh1^T
//  blk 512..543 : XQ    (t=k-2, 2<=k<=65)
//  blk 544..575 : ATT   (t=k-3, 3<=k<=66)
//  blk 576..591 : OUT   (t=k-4, 4<=k<=67)
// ---------------------------------------------------------------------------
__global__ void __launch_bounds__(256) k_phase2(
    const int k,
    const float* __restrict__ gih0,
    const float* __restrict__ Whh0,
    const float* __restrict__ Wih1,
    const float* __restrict__ Whh1,
    const float* __restrict__ bih1,
    const float* __restrict__ bhh1,
    const float* __restrict__ cells,
    const float* __restrict__ h0r, float* __restrict__ h0w,
    const float* __restrict__ h20r, float* __restrict__ h20w,
    const float* __restrict__ h1r, float* __restrict__ h1w,
    float* __restrict__ H2,
    const float* __restrict__ Win, const float* __restrict__ bin,
    float* __restrict__ XQ,
    const float* __restrict__ enc,
    const unsigned char* __restrict__ mask, const int* __restrict__ flag,
    float* __restrict__ CTX,
    const float* __restrict__ Wout, const float* __restrict__ bout,
    float* __restrict__ out)
{
    union Sh {
        struct { float xs[32][516]; float gbuf[8][33]; } ab;
        struct { float xs[32 * 257]; } gm;
        struct { float xq[1024]; float ered[256]; float attn[128]; float red2[8]; } at;
    };
    __shared__ Sh sh;
    const int tid = threadIdx.x;
    const int blk = blockIdx.x;

    if (blk < 256) {                                    // ======== stepA (t=k)
        if (k > 63) return;
        const int b = tid & 31, u = tid >> 5;
        const int d0 = blk * 2;
        const int j = (u >> 1) * 512 + d0 + (u & 1);
        float a = gih0[(size_t)k * 65536 + b * 2048 + j];
        for (int i = tid; i < 4096; i += 256) {
            int b2 = i >> 7, k4 = i & 127;
            *(f4*)&sh.ab.xs[b2][k4 * 4] = *(const f4*)&h0r[b2 * 512 + k4 * 4];
        }
        __syncthreads();
        const float* wp = Whh0 + (size_t)j * 512;
        float s0 = 0, s1 = 0, s2 = 0, s3 = 0;
        for (int kk = 0; kk < 512; kk += 16) {
            f4 x0 = *(const f4*)&sh.ab.xs[b][kk];
            f4 x1 = *(const f4*)&sh.ab.xs[b][kk + 4];
            f4 x2 = *(const f4*)&sh.ab.xs[b][kk + 8];
            f4 x3 = *(const f4*)&sh.ab.xs[b][kk + 12];
            f4 w0 = *(const f4*)&wp[kk];
            f4 w1 = *(const f4*)&wp[kk + 4];
            f4 w2 = *(const f4*)&wp[kk + 8];
            f4 w3 = *(const f4*)&wp[kk + 12];
            s0 += x0[0]*w0[0]; s0 += x0[1]*w0[1]; s0 += x0[2]*w0[2]; s0 += x0[3]*w0[3];
            s1 += x1[0]*w1[0]; s1 += x1[1]*w1[1]; s1 += x1[2]*w1[2]; s1 += x1[3]*w1[3];
            s2 += x2[0]*w2[0]; s2 += x2[1]*w2[1]; s2 += x2[2]*w2[2]; s2 += x2[3]*w2[3];
            s3 += x3[0]*w3[0]; s3 += x3[1]*w3[1]; s3 += x3[2]*w3[2]; s3 += x3[3]*w3[3];
        }
        a += (s0 + s1) + (s2 + s3);
        sh.ab.gbuf[u][b] = a;
        __syncthreads();
        if (tid < 64) {
            int bb = tid & 31, dd = tid >> 5;
            float gi = sh.ab.gbuf[0 + dd][bb], gf = sh.ab.gbuf[2 + dd][bb];
            float gg = sh.ab.gbuf[4 + dd][bb], go = sh.ab.gbuf[6 + dd][bb];
            float cell = cells[bb * 512 + d0 + dd];
            float c2 = sigf(gf) * cell + sigf(gi) * tanhf(gg);
            float h2 = sigf(go) * tanhf(c2);
            h0w[bb * 512 + d0 + dd] = c2;               // faithful bug: carry = cell
            h20w[bb * 512 + d0 + dd] = h2;
        }

    } else if (blk < 512) {                             // ======== stepB (t=k-1)
        if (k < 1 || k > 64) return;
        const int b = tid & 31, u = tid >> 5;
        const int d0 = (blk - 256) * 2;
        const int j = (u >> 1) * 512 + d0 + (u & 1);
        float a = bih1[j] + bhh1[j];
        float s0 = 0, s1 = 0, s2 = 0, s3 = 0;
        // chunk 1: h20 @ Wih1
        for (int i = tid; i < 4096; i += 256) {
            int b2 = i >> 7, k4 = i & 127;
            *(f4*)&sh.ab.xs[b2][k4 * 4] = *(const f4*)&h20r[b2 * 512 + k4 * 4];
        }
        __syncthreads();
        {
            const float* wp = Wih1 + (size_t)j * 512;
            for (int kk = 0; kk < 512; kk += 16) {
                f4 x0 = *(const f4*)&sh.ab.xs[b][kk];
                f4 x1 = *(const f4*)&sh.ab.xs[b][kk + 4];
                f4 x2 = *(const f4*)&sh.ab.xs[b][kk + 8];
                f4 x3 = *(const f4*)&sh.ab.xs[b][kk + 12];
                f4 w0 = *(const f4*)&wp[kk];
                f4 w1 = *(const f4*)&wp[kk + 4];
                f4 w2 = *(const f4*)&wp[kk + 8];
                f4 w3 = *(const f4*)&wp[kk + 12];
                s0 += x0[0]*w0[0]; s0 += x0[1]*w0[1]; s0 += x0[2]*w0[2]; s0 += x0[3]*w0[3];
                s1 += x1[0]*w1[0]; s1 += x1[1]*w1[1]; s1 += x1[2]*w1[2]; s1 += x1[3]*w1[3];
                s2 += x2[0]*w2[0]; s2 += x2[1]*w2[1]; s2 += x2[2]*w2[2]; s2 += x2[3]*w2[3];
                s3 += x3[0]*w3[0]; s3 += x3[1]*w3[1]; s3 += x3[2]*w3[2]; s3 += x3[3]*w3[3];
            }
        }
        __syncthreads();
        // chunk 2: h1 @ Whh1
        for (int i = tid; i < 4096; i += 256) {
            int b2 = i >> 7, k4 = i & 127;
            *(f4*)&sh.ab.xs[b2][k4 * 4] = *(const f4*)&h1r[b2 * 512 + k4 * 4];
        }
        __syncthreads();
        {
            const float* wp = Whh1 + (size_t)j * 512;
            for (int kk = 0; kk < 512; kk += 16) {
                f4 x0 = *(const f4*)&sh.ab.xs[b][kk];
                f4 x1 = *(const f4*)&sh.ab.xs[b][kk + 4];
                f4 x2 = *(const f4*)&sh.ab.xs[b][kk + 8];
                f4 x3 = *(const f4*)&sh.ab.xs[b][kk + 12];
                f4 w0 = *(const f4*)&wp[kk];
                f4 w1 = *(const f4*)&wp[kk + 4];
                f4 w2 = *(const f4*)&wp[kk + 8];
                f4 w3 = *(const f4*)&wp[kk + 12];
                s0 += x0[0]*w0[0]; s0 += x0[1]*w0[1]; s0 += x0[2]*w0[2]; s0 += x0[3]*w0[3];
                s1 += x1[0]*w1[0]; s1 += x1[1]*w1[1]; s1 += x1[2]*w1[2]; s1 += x1[3]*w1[3];
                s2 += x2[0]*w2[0]; s2 += x2[1]*w2[1]; s2 += x2[2]*w2[2]; s2 += x2[3]*w2[3];
                s3 += x3[0]*w3[0]; s3 += x3[1]*w3[1]; s3 += x3[2]*w3[2]; s3 += x3[3]*w3[3];
            }
        }
        a += (s0 + s1) + (s2 + s3);
        sh.ab.gbuf[u][b] = a;
        __syncthreads();
        if (tid < 64) {
            int bb = tid & 31, dd = tid >> 5;
            float gi = sh.ab.gbuf[0 + dd][bb], gf = sh.ab.gbuf[2 + dd][bb];
            float gg = sh.ab.gbuf[4 + dd][bb], go = sh.ab.gbuf[6 + dd][bb];
            float cell = cells[16384 + bb * 512 + d0 + dd];
            float c2 = sigf(gf) * cell + sigf(gi) * tanhf(gg);
            float h2 = sigf(go) * tanhf(c2);
            h1w[bb * 512 + d0 + dd] = c2;               // faithful bug
            H2[(size_t)(k - 1) * 16384 + bb * 512 + d0 + dd] = h2;
        }

    } else if (blk < 544) {                             // ======== XQ (t=k-2)
        if (k < 2 || k > 65) return;
        const int t = k - 2;
        const int j0 = (blk - 512) * 32;
        const int b = tid & 31, jj = tid >> 5;
        float acc[4];
#pragma unroll
        for (int r = 0; r < 4; r++) acc[r] = bin[j0 + jj * 4 + r];
        const float* H2t = H2 + (size_t)t * 16384;
        for (int c = 0; c < 2; c++) {
            for (int idx = tid; idx < 32 * 64; idx += 256) {
                int b2 = idx >> 6, k4 = idx & 63;
                f4 v = *(const f4*)&H2t[b2 * 512 + c * 256 + k4 * 4];
                float* dst = &sh.gm.xs[b2 * 257 + k4 * 4];
                dst[0] = v[0]; dst[1] = v[1]; dst[2] = v[2]; dst[3] = v[3];
            }
            __syncthreads();
            for (int k8 = 0; k8 < 32; k8++) {
                float w[4][8];
#pragma unroll
                for (int r = 0; r < 4; r++) {
                    const f4* wp = (const f4*)&Win[(size_t)(j0 + jj * 4 + r) * 512 + c * 256 + k8 * 8];
                    f4 wa = wp[0], wb = wp[1];
#pragma unroll
                    for (int kk = 0; kk < 4; kk++) { w[r][kk] = wa[kk]; w[r][4 + kk] = wb[kk]; }
                }
#pragma unroll
                for (int kk = 0; kk < 8; kk++) {
                    float xv = sh.gm.xs[b * 257 + k8 * 8 + kk];
#pragma unroll
                    for (int r = 0; r < 4; r++) acc[r] += xv * w[r][kk];
                }
            }
            __syncthreads();
        }
        float* xrow = XQ + ((size_t)(t * 32 + b)) * 1024;
#pragma unroll
        for (int r = 0; r < 4; r++) xrow[j0 + jj * 4 + r] = acc[r];

    } else if (blk < 576) {                             // ======== ATT (t=k-3)
        if (k < 3 || k > 66) return;
        const int t = k - 3;
        const int b = blk - 544;
        {
            f4 v = *(const f4*)&XQ[((size_t)(t * 32 + b)) * 1024 + tid * 4];
            float* dst = &sh.at.xq[tid * 4];
            dst[0] = v[0]; dst[1] = v[1]; dst[2] = v[2]; dst[3] = v[3];
        }
        __syncthreads();
        const int s = tid >> 1, hh = tid & 1;
        float part = 0.f;
        const float* erow = enc + ((size_t)(b * 128 + s)) * 1024 + hh * 512;
        const float* xqh = &sh.at.xq[hh * 512];
        for (int k4 = 0; k4 < 128; k4++) {
            f4 u = *(const f4*)&erow[k4 * 4];
#pragma unroll
            for (int kk = 0; kk < 4; kk++) part += u[kk] * xqh[k4 * 4 + kk];
        }
        sh.at.ered[tid] = part;
        __syncthreads();
        float e = -INFINITY;
        if (tid < 128) {
            e = sh.at.ered[2 * tid] + sh.at.ered[2 * tid + 1];
            int f = *flag;
            bool msk;
            if (f == 0)      msk = mask[b * 128 + tid] != 0;
            else if (f == 1) msk = ((const int*)mask)[b * 128 + tid] != 0;
            else if (f == 2) msk = ((const u16*)mask)[b * 128 + tid] != 0;
            else             msk = ((const unsigned int*)mask)[b * 128 + tid] != 0;
            if (msk) e = -1e9f;
        }
        float v = e;
#pragma unroll
        for (int off = 32; off >= 1; off >>= 1) v = fmaxf(v, __shfl_xor(v, off));
        const int wave = tid >> 6;
        if ((tid & 63) == 0) sh.at.red2[wave] = v;
        __syncthreads();
        float m = fmaxf(fmaxf(sh.at.red2[0], sh.at.red2[1]), fmaxf(sh.at.red2[2], sh.at.red2[3]));
        float p = (tid < 128) ? expf(e - m) : 0.f;
        float su = p;
#pragma unroll
        for (int off = 32; off >= 1; off >>= 1) su += __shfl_xor(su, off);
        __syncthreads();
        if ((tid & 63) == 0) sh.at.red2[4 + wave] = su;
        __syncthreads();
        float S = (sh.at.red2[4] + sh.at.red2[5]) + (sh.at.red2[6] + sh.at.red2[7]);
        if (tid < 128) sh.at.attn[tid] = p / S;
        __syncthreads();
        float c0 = 0, c1 = 0, c2 = 0, c3 = 0;
        const float* eb = enc + ((size_t)b * 128) * 1024 + tid * 4;
        for (int s2 = 0; s2 < 128; s2++) {
            float a = sh.at.attn[s2];
            f4 u = *(const f4*)&eb[(size_t)s2 * 1024];
            c0 += a * u[0]; c1 += a * u[1]; c2 += a * u[2]; c3 += a * u[3];
        }
        float* crow = CTX + ((size_t)(t * 32 + b)) * 1024 + tid * 4;
        crow[0] = c0; crow[1] = c1; crow[2] = c2; crow[3] = c3;

    } else {                                            // ======== OUT (t=k-4)
        if (k < 4 || k > 67) return;
        const int t = k - 4;
        const int j0 = (blk - 576) * 32;
        const int b = tid & 31, jj = tid >> 5;
        float acc[4];
#pragma unroll
        for (int r = 0; r < 4; r++) acc[r] = bout[j0 + jj * 4 + r];
        const float* Ct = CTX + (size_t)t * 32768;
        const float* Ht = H2 + (size_t)t * 16384;
        for (int c = 0; c < 6; c++) {
            for (int idx = tid; idx < 32 * 64; idx += 256) {
                int b2 = idx >> 6, k4 = idx & 63;
                const float* src = (c < 4) ? &Ct[b2 * 1024 + c * 256] : &Ht[b2 * 512 + (c - 4) * 256];
                f4 v = *(const f4*)&src[k4 * 4];
                float* dst = &sh.gm.xs[b2 * 257 + k4 * 4];
                dst[0] = v[0]; dst[1] = v[1]; dst[2] = v[2]; dst[3] = v[3];
            }
            __syncthreads();
            for (int k8 = 0; k8 < 32; k8++) {
                float w[4][8];
#pragma unroll
                for (int r = 0; r < 4; r++) {
                    const f4* wp = (const f4*)&Wout[(size_t)(j0 + jj * 4 + r) * 1536 + c * 256 + k8 * 8];
                    f4 wa = wp[0], wb = wp[1];
#pragma unroll
                    for (int kk = 0; kk < 4; kk++) { w[r][kk] = wa[kk]; w[r][4 + kk] = wb[kk]; }
                }
#pragma unroll
                for (int kk = 0; kk < 8; kk++) {
                    float xv = sh.gm.xs[b * 257 + k8 * 8 + kk];
#pragma unroll
                    for (int r = 0; r < 4; r++) acc[r] += xv * w[r][kk];
                }
            }
            __syncthreads();
        }
        float* orow = out + ((size_t)(t * 32 + b)) * 512;
#pragma unroll
        for (int r = 0; r < 4; r++) orow[j0 + jj * 4 + r] = tanhf(acc[r]);
    }
}

// ---------------------------------------------------------------------------
extern "C" void kernel_launch(void* const* d_in, const int* in_sizes, int n_in,
                              void* d_out, int out_size, void* d_ws, size_t ws_size,
                              hipStream_t stream) {
    const int* tokens   = (const int*)d_in[0];
    const float* enc    = (const float*)d_in[1];
    const float* hidden = (const float*)d_in[2];
    const float* cells  = (const float*)d_in[3];
    const unsigned char* mask = (const unsigned char*)d_in[4];
    const float* embed  = (const float*)d_in[5];
    const float* W_ih   = (const float*)d_in[6];
    const float* W_hh   = (const float*)d_in[7];
    const float* b_ih   = (const float*)d_in[8];
    const float* b_hh   = (const float*)d_in[9];
    const float* W_in   = (const float*)d_in[10];
    const float* b_in   = (const float*)d_in[11];
    const float* W_out  = (const float*)d_in[12];
    const float* b_out  = (const float*)d_in[13];
    float* out = (float*)d_out;

    float* ws = (float*)d_ws;
    float* gih0 = ws;                              // 4,194,304
    float* h0s  = ws + 4194304;                    // 32768 (2 parities)
    float* h20s = ws + 4227072;                    // 32768
    float* h1s  = ws + 4259840;                    // 32768
    float* H2   = ws + 4292608;                    // 1,048,576
    float* XQ   = ws + 5341184;                    // 2,097,152
    float* CTX  = ws + 7438336;                    // 2,097,152
    int*   flag = (int*)(ws + 9535488);

    const float* Whh0 = W_hh;
    const float* Wih1 = W_ih + (size_t)G4_ * DD;
    const float* Whh1 = W_hh + (size_t)G4_ * DD;
    const float* bih1 = b_ih + G4_;
    const float* bhh1 = b_hh + G4_;

    k_flag<<<1, 256, 0, stream>>>(mask, flag);
    k_init2<<<64, 256, 0, stream>>>(hidden, h0s, h1s);
    k_gih0<<<dim3(64, 64), 256, 0, stream>>>(tokens, embed, W_ih, b_ih, b_hh, gih0);

    for (int k = 0; k <= 67; k++) {
        const int r = k & 1, w = r ^ 1;
        k_phase2<<<592, 256, 0, stream>>>(k, gih0, Whh0, Wih1, Whh1, bih1, bhh1, cells,
                                          h0s + r * 16384, h0s + w * 16384,
                                          h20s + r * 16384, h20s + w * 16384,
                                          h1s + r * 16384, h1s + w * 16384,
                                          H2, W_in, b_in, XQ, enc, mask, flag,
                                          CTX, W_out, b_out, out);
    }
}

// Round 9
// 5395.648 us; speedup vs baseline: 7.3531x; 1.9217x over previous
//
#include <hip/hip_runtime.h>
#include <math.h>

typedef unsigned short u16;
typedef __attribute__((ext_vector_type(4))) float f4;

#define BB 32
#define TT 64
#define DD 512
#define G4_ 2048

__device__ __forceinline__ float sigf(float x) { return 1.0f / (1.0f + expf(-x)); }

// ---------------------------------------------------------------------------
// mask dtype classifier: 0=u8(bool), 1=i32, 2=bf16, 3=f32. Deterministic.
// ---------------------------------------------------------------------------
__global__ void k_flag(const unsigned char* __restrict__ m, int* __restrict__ flag) {
    int tid = threadIdx.x;
    int badbyte = 0, nonz_off = 0, evenu16_nz = 0;
    for (int i = tid * 16; i < tid * 16 + 16; i++) {
        unsigned char c = m[i];
        if (c > 1) badbyte = 1;
        if ((i & 3) != 0 && c != 0) nonz_off = 1;
    }
    const u16* mu = (const u16*)m;
    for (int i = tid * 8; i < tid * 8 + 8; i++) {
        if ((i & 1) == 0 && mu[i] != 0) evenu16_nz = 1;
    }
    __shared__ int s_bad, s_noff, s_env;
    if (tid == 0) { s_bad = 0; s_noff = 0; s_env = 0; }
    __syncthreads();
    if (badbyte) atomicOr(&s_bad, 1);
    if (nonz_off) atomicOr(&s_noff, 1);
    if (evenu16_nz) atomicOr(&s_env, 1);
    __syncthreads();
    if (tid == 0) {
        int f;
        if (s_bad) f = s_env ? 2 : 3;
        else       f = s_noff ? 0 : 1;
        *flag = f;
    }
}

// ---------------------------------------------------------------------------
// init: copy initial h-states into both parity buffers.
// ---------------------------------------------------------------------------
__global__ void __launch_bounds__(256) k_init2(const float* __restrict__ hid,
                                               float* __restrict__ h0s,
                                               float* __restrict__ h1s) {
    int i = blockIdx.x * 256 + threadIdx.x;   // 0 .. 16383
    float v0 = hid[i], v1 = hid[16384 + i];
    h0s[i] = v0; h0s[16384 + i] = v0;
    h1s[i] = v1; h1s[16384 + i] = v1;
}

// ---------------------------------------------------------------------------
// gih0[t][b][j] = b_ih0[j] + b_hh0[j] + sum_k embed[tok[b,t],k] * W_ih0[j,k]
// (prologue use: grid (64,1) computes t=0 only)
// ---------------------------------------------------------------------------
__global__ void __launch_bounds__(256) k_gih0(const int* __restrict__ tokens,
                                              const float* __restrict__ embed,
                                              const float* __restrict__ Wih,
                                              const float* __restrict__ bih,
                                              const float* __restrict__ bhh,
                                              float* __restrict__ gih0) {
    const int tid = threadIdx.x;
    const int d0 = blockIdx.x * 8;
    const int t = blockIdx.y;
    const int b = tid & 31, dd = tid >> 5;
    const int d = d0 + dd;
    __shared__ float xs[32 * 257];
    __shared__ int toks[32];
    if (tid < 32) toks[tid] = tokens[tid * TT + t];
    float acc[4];
#pragma unroll
    for (int g = 0; g < 4; g++) { int j = g * 512 + d; acc[g] = bih[j] + bhh[j]; }
    __syncthreads();
    for (int c = 0; c < 2; c++) {
        for (int idx = tid; idx < 32 * 64; idx += 256) {
            int b2 = idx >> 6, k4 = idx & 63;
            f4 v = *(const f4*)&embed[(size_t)toks[b2] * 512 + c * 256 + k4 * 4];
            float* dst = &xs[b2 * 257 + k4 * 4];
            dst[0] = v[0]; dst[1] = v[1]; dst[2] = v[2]; dst[3] = v[3];
        }
        __syncthreads();
        for (int k8 = 0; k8 < 32; k8++) {
            float w[4][8];
#pragma unroll
            for (int g = 0; g < 4; g++) {
                const f4* wp = (const f4*)&Wih[(size_t)(g * 512 + d) * 512 + c * 256 + k8 * 8];
                f4 wa = wp[0], wb = wp[1];
#pragma unroll
                for (int kk = 0; kk < 4; kk++) { w[g][kk] = wa[kk]; w[g][4 + kk] = wb[kk]; }
            }
#pragma unroll
            for (int kk = 0; kk < 8; kk++) {
                float xv = xs[b * 257 + k8 * 8 + kk];
#pragma unroll
                for (int g = 0; g < 4; g++) acc[g] += xv * w[g][kk];
            }
        }
        __syncthreads();
    }
    float* grow = gih0 + ((size_t)(t * 32 + b)) * 2048;
#pragma unroll
    for (int g = 0; g < 4; g++) grow[g * 512 + d] = acc[g];
}

// ---------------------------------------------------------------------------
// Fused phase kernel, launched for k = 0..67. Stream order = grid sync.
//  blk 0..255   : stepA (t=k,   k<=63)   gates = gih0[k] + h0 @ Whh0^T
//  blk 256..511 : stepB (t=k-1, 1<=k<=64) gates = h20@Wih1^T + h1@Whh1^T
//  blk 512..575 : GIH0  (t=k+1, k<=62)   embed-gather GEMM for next phase
//  blk 576..607 : XQ    (t=k-2, 2<=k<=65)
//  blk 608..639 : ATT   (t=k-3, 3<=k<=66)
//  blk 640..655 : OUT   (t=k-4, 4<=k<=67)
// LDS row stride 257 floats (257 % 32 == 1): conflict-free b128 row reads.
// ---------------------------------------------------------------------------
__global__ void __launch_bounds__(256) k_phase3(
    const int k,
    const int* __restrict__ tokens,
    const float* __restrict__ embed,
    const float* __restrict__ Wih0,
    const float* __restrict__ bih0,
    const float* __restrict__ bhh0,
    float* __restrict__ gih0,
    const float* __restrict__ Whh0,
    const float* __restrict__ Wih1,
    const float* __restrict__ Whh1,
    const float* __restrict__ bih1,
    const float* __restrict__ bhh1,
    const float* __restrict__ cells,
    const float* __restrict__ h0r, float* __restrict__ h0w,
    const float* __restrict__ h20r, float* __restrict__ h20w,
    const float* __restrict__ h1r, float* __restrict__ h1w,
    float* __restrict__ H2,
    const float* __restrict__ Win, const float* __restrict__ bin,
    float* __restrict__ XQ,
    const float* __restrict__ enc,
    const unsigned char* __restrict__ mask, const int* __restrict__ flag,
    float* __restrict__ CTX,
    const float* __restrict__ Wout, const float* __restrict__ bout,
    float* __restrict__ out)
{
    union Sh {
        struct { float xs[32][257]; float gbuf[8][33]; } ab;
        struct { float xs[32 * 257]; int toks[32]; } g;
        struct { float xs[32 * 257]; } gm;
        struct { float xq[1024]; float ered[256]; float attn[128]; float red2[8]; } at;
    };
    __shared__ Sh sh;
    const int tid = threadIdx.x;
    const int blk = blockIdx.x;

    if (blk < 256) {                                    // ======== stepA (t=k)
        if (k > 63) return;
        const int b = tid & 31, u = tid >> 5;
        const int d0 = blk * 2;
        const int j = (u >> 1) * 512 + d0 + (u & 1);
        float a = gih0[(size_t)k * 65536 + b * 2048 + j];
        const float* WA = Whh0 + (size_t)j * 512;
        for (int c = 0; c < 2; c++) {
            __syncthreads();
            for (int i = tid; i < 2048; i += 256) {
                int b2 = i >> 6, k4 = i & 63;
                *(f4*)&sh.ab.xs[b2][k4 * 4] = *(const f4*)&h0r[b2 * 512 + c * 256 + k4 * 4];
            }
            __syncthreads();
            const float* wp = WA + c * 256;
            for (int k4 = 0; k4 < 64; k4++) {
                f4 x = *(const f4*)&sh.ab.xs[b][k4 * 4];
                f4 w = *(const f4*)&wp[k4 * 4];
                a += x[0] * w[0]; a += x[1] * w[1]; a += x[2] * w[2]; a += x[3] * w[3];
            }
        }
        sh.ab.gbuf[u][b] = a;
        __syncthreads();
        if (tid < 64) {
            int bb = tid & 31, dd = tid >> 5;
            float gi = sh.ab.gbuf[0 + dd][bb], gf = sh.ab.gbuf[2 + dd][bb];
            float gg = sh.ab.gbuf[4 + dd][bb], go = sh.ab.gbuf[6 + dd][bb];
            float cell = cells[bb * 512 + d0 + dd];
            float c2 = sigf(gf) * cell + sigf(gi) * tanhf(gg);
            float h2 = sigf(go) * tanhf(c2);
            h0w[bb * 512 + d0 + dd] = c2;               // faithful bug: carry = cell
            h20w[bb * 512 + d0 + dd] = h2;
        }

    } else if (blk < 512) {                             // ======== stepB (t=k-1)
        if (k < 1 || k > 64) return;
        const int b = tid & 31, u = tid >> 5;
        const int d0 = (blk - 256) * 2;
        const int j = (u >> 1) * 512 + d0 + (u & 1);
        float a = bih1[j] + bhh1[j];
        const float* WI = Wih1 + (size_t)j * 512;
        const float* WH = Whh1 + (size_t)j * 512;
        for (int c = 0; c < 4; c++) {
            const float* srcb = (c < 2) ? h20r : h1r;
            const int off = (c & 1) * 256;
            const float* wp = ((c < 2) ? WI : WH) + off;
            __syncthreads();
            for (int i = tid; i < 2048; i += 256) {
                int b2 = i >> 6, k4 = i & 63;
                *(f4*)&sh.ab.xs[b2][k4 * 4] = *(const f4*)&srcb[b2 * 512 + off + k4 * 4];
            }
            __syncthreads();
            for (int k4 = 0; k4 < 64; k4++) {
                f4 x = *(const f4*)&sh.ab.xs[b][k4 * 4];
                f4 w = *(const f4*)&wp[k4 * 4];
                a += x[0] * w[0]; a += x[1] * w[1]; a += x[2] * w[2]; a += x[3] * w[3];
            }
        }
        sh.ab.gbuf[u][b] = a;
        __syncthreads();
        if (tid < 64) {
            int bb = tid & 31, dd = tid >> 5;
            float gi = sh.ab.gbuf[0 + dd][bb], gf = sh.ab.gbuf[2 + dd][bb];
            float gg = sh.ab.gbuf[4 + dd][bb], go = sh.ab.gbuf[6 + dd][bb];
            float cell = cells[16384 + bb * 512 + d0 + dd];
            float c2 = sigf(gf) * cell + sigf(gi) * tanhf(gg);
            float h2 = sigf(go) * tanhf(c2);
            h1w[bb * 512 + d0 + dd] = c2;               // faithful bug
            H2[(size_t)(k - 1) * 16384 + bb * 512 + d0 + dd] = h2;
        }

    } else if (blk < 576) {                             // ======== GIH0 (t=k+1)
        if (k > 62) return;
        const int t = k + 1;
        const int d0 = (blk - 512) * 8;
        const int b = tid & 31, dd = tid >> 5;
        const int d = d0 + dd;
        if (tid < 32) sh.g.toks[tid] = tokens[tid * TT + t];
        float acc[4];
#pragma unroll
        for (int g = 0; g < 4; g++) { int j = g * 512 + d; acc[g] = bih0[j] + bhh0[j]; }
        __syncthreads();
        for (int c = 0; c < 2; c++) {
            for (int idx = tid; idx < 32 * 64; idx += 256) {
                int b2 = idx >> 6, k4 = idx & 63;
                f4 v = *(const f4*)&embed[(size_t)sh.g.toks[b2] * 512 + c * 256 + k4 * 4];
                float* dst = &sh.g.xs[b2 * 257 + k4 * 4];
                dst[0] = v[0]; dst[1] = v[1]; dst[2] = v[2]; dst[3] = v[3];
            }
            __syncthreads();
            for (int k8 = 0; k8 < 32; k8++) {
                float w[4][8];
#pragma unroll
                for (int g = 0; g < 4; g++) {
                    const f4* wp = (const f4*)&Wih0[(size_t)(g * 512 + d) * 512 + c * 256 + k8 * 8];
                    f4 wa = wp[0], wb = wp[1];
#pragma unroll
                    for (int kk = 0; kk < 4; kk++) { w[g][kk] = wa[kk]; w[g][4 + kk] = wb[kk]; }
                }
#pragma unroll
                for (int kk = 0; kk < 8; kk++) {
                    float xv = sh.g.xs[b * 257 + k8 * 8 + kk];
#pragma unroll
                    for (int g = 0; g < 4; g++) acc[g] += xv * w[g][kk];
                }
            }
            __syncthreads();
        }
        float* grow = gih0 + ((size_t)(t * 32 + b)) * 2048;
#pragma unroll
        for (int g = 0; g < 4; g++) grow[g * 512 + d] = acc[g];

    } else if (blk < 608) {                             // ======== XQ (t=k-2)
        if (k < 2 || k > 65) return;
        const int t = k - 2;
        const int j0 = (blk - 576) * 32;
        const int b = tid & 31, jj = tid >> 5;
        float acc[4];
#pragma unroll
        for (int r = 0; r < 4; r++) acc[r] = bin[j0 + jj * 4 + r];
        const float* H2t = H2 + (size_t)t * 16384;
        for (int c = 0; c < 2; c++) {
            for (int idx = tid; idx < 32 * 64; idx += 256) {
                int b2 = idx >> 6, k4 = idx & 63;
                f4 v = *(const f4*)&H2t[b2 * 512 + c * 256 + k4 * 4];
                float* dst = &sh.gm.xs[b2 * 257 + k4 * 4];
                dst[0] = v[0]; dst[1] = v[1]; dst[2] = v[2]; dst[3] = v[3];
            }
            __syncthreads();
            for (int k8 = 0; k8 < 32; k8++) {
                float w[4][8];
#pragma unroll
                for (int r = 0; r < 4; r++) {
                    const f4* wp = (const f4*)&Win[(size_t)(j0 + jj * 4 + r) * 512 + c * 256 + k8 * 8];
                    f4 wa = wp[0], wb = wp[1];
#pragma unroll
                    for (int kk = 0; kk < 4; kk++) { w[r][kk] = wa[kk]; w[r][4 + kk] = wb[kk]; }
                }
#pragma unroll
                for (int kk = 0; kk < 8; kk++) {
                    float xv = sh.gm.xs[b * 257 + k8 * 8 + kk];
#pragma unroll
                    for (int r = 0; r < 4; r++) acc[r] += xv * w[r][kk];
                }
            }
            __syncthreads();
        }
        float* xrow = XQ + ((size_t)(t * 32 + b)) * 1024;
#pragma unroll
        for (int r = 0; r < 4; r++) xrow[j0 + jj * 4 + r] = acc[r];

    } else if (blk < 640) {                             // ======== ATT (t=k-3)
        if (k < 3 || k > 66) return;
        const int t = k - 3;
        const int b = blk - 608;
        {
            f4 v = *(const f4*)&XQ[((size_t)(t * 32 + b)) * 1024 + tid * 4];
            float* dst = &sh.at.xq[tid * 4];
            dst[0] = v[0]; dst[1] = v[1]; dst[2] = v[2]; dst[3] = v[3];
        }
        __syncthreads();
        const int s = tid >> 1, hh = tid & 1;
        float part = 0.f;
        const float* erow = enc + ((size_t)(b * 128 + s)) * 1024 + hh * 512;
        const float* xqh = &sh.at.xq[hh * 512];
        for (int k4 = 0; k4 < 128; k4++) {
            f4 u = *(const f4*)&erow[k4 * 4];
#pragma unroll
            for (int kk = 0; kk < 4; kk++) part += u[kk] * xqh[k4 * 4 + kk];
        }
        sh.at.ered[tid] = part;
        __syncthreads();
        float e = -INFINITY;
        if (tid < 128) {
            e = sh.at.ered[2 * tid] + sh.at.ered[2 * tid + 1];
            int f = *flag;
            bool msk;
            if (f == 0)      msk = mask[b * 128 + tid] != 0;
            else if (f == 1) msk = ((const int*)mask)[b * 128 + tid] != 0;
            else if (f == 2) msk = ((const u16*)mask)[b * 128 + tid] != 0;
            else             msk = ((const unsigned int*)mask)[b * 128 + tid] != 0;
            if (msk) e = -1e9f;
        }
        float v = e;
#pragma unroll
        for (int off = 32; off >= 1; off >>= 1) v = fmaxf(v, __shfl_xor(v, off));
        const int wave = tid >> 6;
        if ((tid & 63) == 0) sh.at.red2[wave] = v;
        __syncthreads();
        float m = fmaxf(fmaxf(sh.at.red2[0], sh.at.red2[1]), fmaxf(sh.at.red2[2], sh.at.red2[3]));
        float p = (tid < 128) ? expf(e - m) : 0.f;
        float su = p;
#pragma unroll
        for (int off = 32; off >= 1; off >>= 1) su += __shfl_xor(su, off);
        __syncthreads();
        if ((tid & 63) == 0) sh.at.red2[4 + wave] = su;
        __syncthreads();
        float S = (sh.at.red2[4] + sh.at.red2[5]) + (sh.at.red2[6] + sh.at.red2[7]);
        if (tid < 128) sh.at.attn[tid] = p / S;
        __syncthreads();
        float c0 = 0, c1 = 0, c2 = 0, c3 = 0;
        const float* eb = enc + ((size_t)b * 128) * 1024 + tid * 4;
        for (int s2 = 0; s2 < 128; s2++) {
            float a = sh.at.attn[s2];
            f4 u = *(const f4*)&eb[(size_t)s2 * 1024];
            c0 += a * u[0]; c1 += a * u[1]; c2 += a * u[2]; c3 += a * u[3];
        }
        float* crow = CTX + ((size_t)(t * 32 + b)) * 1024 + tid * 4;
        crow[0] = c0; crow[1] = c1; crow[2] = c2; crow[3] = c3;

    } else {                                            // ======== OUT (t=k-4)
        if (k < 4 || k > 67) return;
        const int t = k - 4;
        const int j0 = (blk - 640) * 32;
        const int b = tid & 31, jj = tid >> 5;
        float acc[4];
#pragma unroll
        for (int r = 0; r < 4; r++) acc[r] = bout[j0 + jj * 4 + r];
        const float* Ct = CTX + (size_t)t * 32768;
        const float* Ht = H2 + (size_t)t * 16384;
        for (int c = 0; c < 6; c++) {
            for (int idx = tid; idx < 32 * 64; idx += 256) {
                int b2 = idx >> 6, k4 = idx & 63;
                const float* src = (c < 4) ? &Ct[b2 * 1024 + c * 256] : &Ht[b2 * 512 + (c - 4) * 256];
                f4 v = *(const f4*)&src[k4 * 4];
                float* dst = &sh.gm.xs[b2 * 257 + k4 * 4];
                dst[0] = v[0]; dst[1] = v[1]; dst[2] = v[2]; dst[3] = v[3];
            }
            __syncthreads();
            for (int k8 = 0; k8 < 32; k8++) {
                float w[4][8];
#pragma unroll
                for (int r = 0; r < 4; r++) {
                    const f4* wp = (const f4*)&Wout[(size_t)(j0 + jj * 4 + r) * 1536 + c * 256 + k8 * 8];
                    f4 wa = wp[0], wb = wp[1];
#pragma unroll
                    for (int kk = 0; kk < 4; kk++) { w[r][kk] = wa[kk]; w[r][4 + kk] = wb[kk]; }
                }
#pragma unroll
                for (int kk = 0; kk < 8; kk++) {
                    float xv = sh.gm.xs[b * 257 + k8 * 8 + kk];
#pragma unroll
                    for (int r = 0; r < 4; r++) acc[r] += xv * w[r][kk];
                }
            }
            __syncthreads();
        }
        float* orow = out + ((size_t)(t * 32 + b)) * 512;
#pragma unroll
        for (int r = 0; r < 4; r++) orow[j0 + jj * 4 + r] = tanhf(acc[r]);
    }
}

// ---------------------------------------------------------------------------
extern "C" void kernel_launch(void* const* d_in, const int* in_sizes, int n_in,
                              void* d_out, int out_size, void* d_ws, size_t ws_size,
                              hipStream_t stream) {
    const int* tokens   = (const int*)d_in[0];
    const float* enc    = (const float*)d_in[1];
    const float* hidden = (const float*)d_in[2];
    const float* cells  = (const float*)d_in[3];
    const unsigned char* mask = (const unsigned char*)d_in[4];
    const float* embed  = (const float*)d_in[5];
    const float* W_ih   = (const float*)d_in[6];
    const float* W_hh   = (const float*)d_in[7];
    const float* b_ih   = (const float*)d_in[8];
    const float* b_hh   = (const float*)d_in[9];
    const float* W_in   = (const float*)d_in[10];
    const float* b_in   = (const float*)d_in[11];
    const float* W_out  = (const float*)d_in[12];
    const float* b_out  = (const float*)d_in[13];
    float* out = (float*)d_out;

    float* ws = (float*)d_ws;
    float* gih0 = ws;                              // 4,194,304
    float* h0s  = ws + 4194304;                    // 32768 (2 parities)
    float* h20s = ws + 4227072;                    // 32768
    float* h1s  = ws + 4259840;                    // 32768
    float* H2   = ws + 4292608;                    // 1,048,576
    float* XQ   = ws + 5341184;                    // 2,097,152
    float* CTX  = ws + 7438336;                    // 2,097,152
    int*   flag = (int*)(ws + 9535488);

    const float* Whh0 = W_hh;
    const float* Wih1 = W_ih + (size_t)G4_ * DD;
    const float* Whh1 = W_hh + (size_t)G4_ * DD;
    const float* bih1 = b_ih + G4_;
    const float* bhh1 = b_hh + G4_;

    k_flag<<<1, 256, 0, stream>>>(mask, flag);
    k_init2<<<64, 256, 0, stream>>>(hidden, h0s, h1s);
    k_gih0<<<dim3(64, 1), 256, 0, stream>>>(tokens, embed, W_ih, b_ih, b_hh, gih0);  // t=0

    for (int k = 0; k <= 67; k++) {
        const int r = k & 1, w = r ^ 1;
        k_phase3<<<656, 256, 0, stream>>>(k, tokens, embed, W_ih, b_ih, b_hh, gih0,
                                          Whh0, Wih1, Whh1, bih1, bhh1, cells,
                                          h0s + r * 16384, h0s + w * 16384,
                                          h20s + r * 16384, h20s + w * 16384,
                                          h1s + r * 16384, h1s + w * 16384,
                                          H2, W_in, b_in, XQ, enc, mask, flag,
                                          CTX, W_out, b_out, out);
    }
}

// Round 10
// 1830.668 us; speedup vs baseline: 21.6721x; 2.9474x over previous
//
#include <hip/hip_runtime.h>
#include <math.h>

typedef unsigned short u16;
typedef __attribute__((ext_vector_type(4))) float f4;
typedef __attribute__((ext_vector_type(8))) unsigned short us8;

#define BB 32
#define TT 64
#define DD 512
#define G4_ 2048

__device__ __forceinline__ float sigf(float x) { return 1.0f / (1.0f + expf(-x)); }
__device__ __forceinline__ float bf2f(u16 u) {
    union { unsigned int i; float f; } v; v.i = ((unsigned int)u) << 16; return v.f;
}
__device__ __forceinline__ u16 f2bf(float f) {
    union { float f; unsigned int i; } v; v.f = f;
    unsigned int r = v.i + 0x7fffu + ((v.i >> 16) & 1u);
    return (u16)(r >> 16);
}

// ---------------------------------------------------------------------------
// mask dtype classifier: 0=u8(bool), 1=i32, 2=bf16, 3=f32. Deterministic.
// ---------------------------------------------------------------------------
__global__ void k_flag(const unsigned char* __restrict__ m, int* __restrict__ flag) {
    int tid = threadIdx.x;
    int badbyte = 0, nonz_off = 0, evenu16_nz = 0;
    for (int i = tid * 16; i < tid * 16 + 16; i++) {
        unsigned char c = m[i];
        if (c > 1) badbyte = 1;
        if ((i & 3) != 0 && c != 0) nonz_off = 1;
    }
    const u16* mu = (const u16*)m;
    for (int i = tid * 8; i < tid * 8 + 8; i++) {
        if ((i & 1) == 0 && mu[i] != 0) evenu16_nz = 1;
    }
    __shared__ int s_bad, s_noff, s_env;
    if (tid == 0) { s_bad = 0; s_noff = 0; s_env = 0; }
    __syncthreads();
    if (badbyte) atomicOr(&s_bad, 1);
    if (nonz_off) atomicOr(&s_noff, 1);
    if (evenu16_nz) atomicOr(&s_env, 1);
    __syncthreads();
    if (tid == 0) {
        int f;
        if (s_bad) f = s_env ? 2 : 3;
        else       f = s_noff ? 0 : 1;
        *flag = f;
    }
}

// ---------------------------------------------------------------------------
// init: copy initial h-states into both parity buffers.
// ---------------------------------------------------------------------------
__global__ void __launch_bounds__(256) k_init2(const float* __restrict__ hid,
                                               float* __restrict__ h0s,
                                               float* __restrict__ h1s) {
    int i = blockIdx.x * 256 + threadIdx.x;   // 0 .. 16383
    float v0 = hid[i], v1 = hid[16384 + i];
    h0s[i] = v0; h0s[16384 + i] = v0;
    h1s[i] = v1; h1s[16384 + i] = v1;
}

// ---------------------------------------------------------------------------
// convert the 4 recurrent weight matrices to bf16 (RNE).
// dst layout: [wih0 | whh0 | wih1 | whh1], each 2048*512 u16.
// grid 4096 x 256 thr, 4 elems/thread.
// ---------------------------------------------------------------------------
__global__ void __launch_bounds__(256) k_conv(const float* __restrict__ Wih,
                                              const float* __restrict__ Whh,
                                              u16* __restrict__ dst) {
    size_t idx = ((size_t)blockIdx.x * 256 + threadIdx.x) * 4;   // 0..4194300
    int m = (int)(idx >> 20);
    size_t off = idx & 1048575;
    const float* src = (m == 0) ? Wih
                     : (m == 1) ? Whh
                     : (m == 2) ? (Wih + 1048576)
                                : (Whh + 1048576);
    f4 v = *(const f4*)&src[off];
    dst[idx + 0] = f2bf(v[0]);
    dst[idx + 1] = f2bf(v[1]);
    dst[idx + 2] = f2bf(v[2]);
    dst[idx + 3] = f2bf(v[3]);
}

// ---------------------------------------------------------------------------
// gih0[t][b][j] = b_ih0[j] + b_hh0[j] + sum_k embed[tok[b,t],k] * W_ih0[j,k]
// W_ih0 in bf16. grid (64 dtiles, 64 t), 256 thr.
// ---------------------------------------------------------------------------
__global__ void __launch_bounds__(256) k_gih0(const int* __restrict__ tokens,
                                              const float* __restrict__ embed,
                                              const u16* __restrict__ Wih0b,
                                              const float* __restrict__ bih,
                                              const float* __restrict__ bhh,
                                              float* __restrict__ gih0) {
    const int tid = threadIdx.x;
    const int d0 = blockIdx.x * 8;
    const int t = blockIdx.y;
    const int b = tid & 31, dd = tid >> 5;
    const int d = d0 + dd;
    __shared__ float xs[32 * 257];
    __shared__ int toks[32];
    if (tid < 32) toks[tid] = tokens[tid * TT + t];
    float acc[4];
#pragma unroll
    for (int g = 0; g < 4; g++) { int j = g * 512 + d; acc[g] = bih[j] + bhh[j]; }
    __syncthreads();
    for (int c = 0; c < 2; c++) {
        for (int idx = tid; idx < 32 * 64; idx += 256) {
            int b2 = idx >> 6, k4 = idx & 63;
            f4 v = *(const f4*)&embed[(size_t)toks[b2] * 512 + c * 256 + k4 * 4];
            float* dst = &xs[b2 * 257 + k4 * 4];
            dst[0] = v[0]; dst[1] = v[1]; dst[2] = v[2]; dst[3] = v[3];
        }
        __syncthreads();
        for (int k8 = 0; k8 < 32; k8++) {
            float w[4][8];
#pragma unroll
            for (int g = 0; g < 4; g++) {
                us8 wv = *(const us8*)&Wih0b[(size_t)(g * 512 + d) * 512 + c * 256 + k8 * 8];
#pragma unroll
                for (int kk = 0; kk < 8; kk++) w[g][kk] = bf2f(wv[kk]);
            }
#pragma unroll
            for (int kk = 0; kk < 8; kk++) {
                float xv = xs[b * 257 + k8 * 8 + kk];
#pragma unroll
                for (int g = 0; g < 4; g++) acc[g] += xv * w[g][kk];
            }
        }
        __syncthreads();
    }
    float* grow = gih0 + ((size_t)(t * 32 + b)) * 2048;
#pragma unroll
    for (int g = 0; g < 4; g++) grow[g * 512 + d] = acc[g];
}

// ---------------------------------------------------------------------------
// Fused phase kernel (launched 65x; stream order = the grid sync).
// blocks [0,256):  stepA(t=k)   (k<64): gates = gih0[k] + h0 @ Whh0^T
// blocks [256,512): stepB(t=k-1)(k>=1): gates = h20@Wih1^T + h1@Whh1^T
// Weights bf16; h-state, biases, gates f32. Summation order == R6 (sequential
// over k within each 256-col chunk).
// ---------------------------------------------------------------------------
__global__ void __launch_bounds__(256) k_phase(
    const int k,
    const float* __restrict__ gih0,
    const u16* __restrict__ Whh0b,
    const u16* __restrict__ Wih1b,
    const u16* __restrict__ Whh1b,
    const float* __restrict__ bih1,
    const float* __restrict__ bhh1,
    const float* __restrict__ cells,
    const float* __restrict__ h0r, float* __restrict__ h0w,
    const float* __restrict__ h20r, float* __restrict__ h20w,
    const float* __restrict__ h1r, float* __restrict__ h1w,
    float* __restrict__ H2)
{
    const int tid = threadIdx.x;
    const int b = tid & 31, u = tid >> 5;       // u = row m, 0..7
    __shared__ float xs[32][257];
    __shared__ float gbuf[8][33];

    if (blockIdx.x < 256) {                     // ======== stepA (t = k)
        if (k >= 64) return;
        const int d0 = blockIdx.x * 2;
        const int j = (u >> 1) * 512 + d0 + (u & 1);
        float a = gih0[(size_t)k * 65536 + b * 2048 + j];
        const u16* WA = Whh0b + (size_t)j * 512;
        for (int c = 0; c < 2; c++) {
            __syncthreads();
            for (int i = tid; i < 2048; i += 256) {
                int b2 = i >> 6, k4 = i & 63;
                *(f4*)&xs[b2][k4 * 4] = *(const f4*)&h0r[b2 * 512 + c * 256 + k4 * 4];
            }
            __syncthreads();
            const u16* wp = WA + c * 256;
            for (int k8 = 0; k8 < 32; k8++) {
                us8 wv = *(const us8*)&wp[k8 * 8];
                f4 x0 = *(const f4*)&xs[b][k8 * 8];
                f4 x1 = *(const f4*)&xs[b][k8 * 8 + 4];
                a += x0[0] * bf2f(wv[0]); a += x0[1] * bf2f(wv[1]);
                a += x0[2] * bf2f(wv[2]); a += x0[3] * bf2f(wv[3]);
                a += x1[0] * bf2f(wv[4]); a += x1[1] * bf2f(wv[5]);
                a += x1[2] * bf2f(wv[6]); a += x1[3] * bf2f(wv[7]);
            }
        }
        gbuf[u][b] = a;
        __syncthreads();
        if (tid < 64) {
            int bb = tid & 31, dd = tid >> 5;   // dd 0..1
            float gi = gbuf[0 + dd][bb], gf = gbuf[2 + dd][bb];
            float gg = gbuf[4 + dd][bb], go = gbuf[6 + dd][bb];
            float cell = cells[bb * 512 + d0 + dd];
            float c2 = sigf(gf) * cell + sigf(gi) * tanhf(gg);
            float h2 = sigf(go) * tanhf(c2);
            h0w[bb * 512 + d0 + dd] = c2;       // faithful bug: carry = cell
            h20w[bb * 512 + d0 + dd] = h2;
        }
    } else {                                    // ======== stepB (t = k-1)
        if (k < 1) return;
        const int d0 = (blockIdx.x - 256) * 2;
        const int j = (u >> 1) * 512 + d0 + (u & 1);
        float a = bih1[j] + bhh1[j];
        const u16* WI = Wih1b + (size_t)j * 512;
        const u16* WH = Whh1b + (size_t)j * 512;
        for (int c = 0; c < 4; c++) {
            const float* srcb = (c < 2) ? h20r : h1r;
            const int off = (c & 1) * 256;
            const u16* wp = ((c < 2) ? WI : WH) + off;
            __syncthreads();
            for (int i = tid; i < 2048; i += 256) {
                int b2 = i >> 6, k4 = i & 63;
                *(f4*)&xs[b2][k4 * 4] = *(const f4*)&srcb[b2 * 512 + off + k4 * 4];
            }
            __syncthreads();
            for (int k8 = 0; k8 < 32; k8++) {
                us8 wv = *(const us8*)&wp[k8 * 8];
                f4 x0 = *(const f4*)&xs[b][k8 * 8];
                f4 x1 = *(const f4*)&xs[b][k8 * 8 + 4];
                a += x0[0] * bf2f(wv[0]); a += x0[1] * bf2f(wv[1]);
                a += x0[2] * bf2f(wv[2]); a += x0[3] * bf2f(wv[3]);
                a += x1[0] * bf2f(wv[4]); a += x1[1] * bf2f(wv[5]);
                a += x1[2] * bf2f(wv[6]); a += x1[3] * bf2f(wv[7]);
            }
        }
        gbuf[u][b] = a;
        __syncthreads();
        if (tid < 64) {
            int bb = tid & 31, dd = tid >> 5;   // dd 0..1
            float gi = gbuf[0 + dd][bb], gf = gbuf[2 + dd][bb];
            float gg = gbuf[4 + dd][bb], go = gbuf[6 + dd][bb];
            float cell = cells[16384 + bb * 512 + d0 + dd];
            float c2 = sigf(gf) * cell + sigf(gi) * tanhf(gg);
            float h2 = sigf(go) * tanhf(c2);
            h1w[bb * 512 + d0 + dd] = c2;       // faithful bug
            H2[(size_t)(k - 1) * 16384 + bb * 512 + d0 + dd] = h2;
        }
    }
}

// ---------------------------------------------------------------------------
// XQ[t,b,:] = H2[t,b,:] @ W_in^T + b_in   (f32, batched)
// ---------------------------------------------------------------------------
__global__ void __launch_bounds__(256) k_x(const float* __restrict__ H2,
                                           const float* __restrict__ Win,
                                           const float* __restrict__ bin,
                                           float* __restrict__ XQ) {
    const int tid = threadIdx.x;
    const int j0 = blockIdx.x * 32;
    const int t = blockIdx.y;
    const int b = tid & 31, jj = tid >> 5;
    __shared__ float xs[32 * 257];
    float acc[4];
#pragma unroll
    for (int r = 0; r < 4; r++) acc[r] = bin[j0 + jj * 4 + r];
    const float* H2t = H2 + (size_t)t * 32 * 512;
    for (int c = 0; c < 2; c++) {
        for (int idx = tid; idx < 32 * 64; idx += 256) {
            int b2 = idx >> 6, k4 = idx & 63;
            f4 v = *(const f4*)&H2t[b2 * 512 + c * 256 + k4 * 4];
            float* dst = &xs[b2 * 257 + k4 * 4];
            dst[0] = v[0]; dst[1] = v[1]; dst[2] = v[2]; dst[3] = v[3];
        }
        __syncthreads();
        for (int k8 = 0; k8 < 32; k8++) {
            float w[4][8];
#pragma unroll
            for (int r = 0; r < 4; r++) {
                const f4* wp = (const f4*)&Win[(size_t)(j0 + jj * 4 + r) * 512 + c * 256 + k8 * 8];
                f4 wa = wp[0], wb = wp[1];
#pragma unroll
                for (int kk = 0; kk < 4; kk++) { w[r][kk] = wa[kk]; w[r][4 + kk] = wb[kk]; }
            }
#pragma unroll
            for (int kk = 0; kk < 8; kk++) {
                float xv = xs[b * 257 + k8 * 8 + kk];
#pragma unroll
                for (int r = 0; r < 4; r++) acc[r] += xv * w[r][kk];
            }
        }
        __syncthreads();
    }
    float* xrow = XQ + ((size_t)(t * 32 + b)) * 1024;
#pragma unroll
    for (int r = 0; r < 4; r++) xrow[j0 + jj * 4 + r] = acc[r];
}

// ---------------------------------------------------------------------------
// attention per (t,b): e = enc . xq, masked softmax, ctx = attn . enc
// ---------------------------------------------------------------------------
__global__ void __launch_bounds__(256) k_att(const float* __restrict__ XQ,
                                             const float* __restrict__ enc,
                                             const unsigned char* __restrict__ mask,
                                             const int* __restrict__ flag,
                                             float* __restrict__ CTX) {
    const int tid = threadIdx.x;
    const int b = blockIdx.x, t = blockIdx.y;
    __shared__ float xq[1024];
    __shared__ float ered[256];
    __shared__ float attn[128];
    __shared__ float red2[8];
    {
        f4 v = *(const f4*)&XQ[((size_t)(t * 32 + b)) * 1024 + tid * 4];
        float* dst = &xq[tid * 4];
        dst[0] = v[0]; dst[1] = v[1]; dst[2] = v[2]; dst[3] = v[3];
    }
    __syncthreads();
    const int s = tid >> 1, hh = tid & 1;
    float part = 0.f;
    const float* erow = enc + ((size_t)(b * 128 + s)) * 1024 + hh * 512;
    const float* xqh = &xq[hh * 512];
    for (int k4 = 0; k4 < 128; k4++) {
        f4 u = *(const f4*)&erow[k4 * 4];
#pragma unroll
        for (int kk = 0; kk < 4; kk++) part += u[kk] * xqh[k4 * 4 + kk];
    }
    ered[tid] = part;
    __syncthreads();
    float e = -INFINITY;
    if (tid < 128) {
        e = ered[2 * tid] + ered[2 * tid + 1];
        int f = *flag;
        bool msk;
        if (f == 0)      msk = mask[b * 128 + tid] != 0;
        else if (f == 1) msk = ((const int*)mask)[b * 128 + tid] != 0;
        else if (f == 2) msk = ((const u16*)mask)[b * 128 + tid] != 0;
        else             msk = ((const unsigned int*)mask)[b * 128 + tid] != 0;
        if (msk) e = -1e9f;
    }
    float v = e;
#pragma unroll
    for (int off = 32; off >= 1; off >>= 1) v = fmaxf(v, __shfl_xor(v, off));
    const int wave = tid >> 6;
    if ((tid & 63) == 0) red2[wave] = v;
    __syncthreads();
    float m = fmaxf(fmaxf(red2[0], red2[1]), fmaxf(red2[2], red2[3]));
    float p = (tid < 128) ? expf(e - m) : 0.f;
    float su = p;
#pragma unroll
    for (int off = 32; off >= 1; off >>= 1) su += __shfl_xor(su, off);
    __syncthreads();
    if ((tid & 63) == 0) red2[4 + wave] = su;
    __syncthreads();
    float S = (red2[4] + red2[5]) + (red2[6] + red2[7]);
    if (tid < 128) attn[tid] = p / S;
    __syncthreads();
    float c0 = 0, c1 = 0, c2 = 0, c3 = 0;
    const float* eb = enc + ((size_t)b * 128) * 1024 + tid * 4;
    for (int s2 = 0; s2 < 128; s2++) {
        float a = attn[s2];
        f4 u = *(const f4*)&eb[(size_t)s2 * 1024];
        c0 += a * u[0]; c1 += a * u[1]; c2 += a * u[2]; c3 += a * u[3];
    }
    float* crow = CTX + ((size_t)(t * 32 + b)) * 1024 + tid * 4;
    crow[0] = c0; crow[1] = c1; crow[2] = c2; crow[3] = c3;
}

// ---------------------------------------------------------------------------
// out[t,b,:] = tanh([ctx, s] @ W_out^T + b_out)  -> f32 d_out
// ---------------------------------------------------------------------------
__global__ void __launch_bounds__(256) k_out(const float* __restrict__ CTX,
                                             const float* __restrict__ H2,
                                             const float* __restrict__ Wout,
                                             const float* __restrict__ bout,
                                             float* __restrict__ out) {
    const int tid = threadIdx.x;
    const int j0 = blockIdx.x * 32;
    const int t = blockIdx.y;
    const int b = tid & 31, jj = tid >> 5;
    __shared__ float xs[32 * 257];
    float acc[4];
#pragma unroll
    for (int r = 0; r < 4; r++) acc[r] = bout[j0 + jj * 4 + r];
    const float* Ct = CTX + (size_t)t * 32 * 1024;
    const float* Ht = H2 + (size_t)t * 32 * 512;
    for (int c = 0; c < 6; c++) {
        for (int idx = tid; idx < 32 * 64; idx += 256) {
            int b2 = idx >> 6, k4 = idx & 63;
            const float* src = (c < 4) ? &Ct[b2 * 1024 + c * 256] : &Ht[b2 * 512 + (c - 4) * 256];
            f4 v = *(const f4*)&src[k4 * 4];
            float* dst = &xs[b2 * 257 + k4 * 4];
            dst[0] = v[0]; dst[1] = v[1]; dst[2] = v[2]; dst[3] = v[3];
        }
        __syncthreads();
        for (int k8 = 0; k8 < 32; k8++) {
            float w[4][8];
#pragma unroll
            for (int r = 0; r < 4; r++) {
                const f4* wp = (const f4*)&Wout[(size_t)(j0 + jj * 4 + r) * 1536 + c * 256 + k8 * 8];
                f4 wa = wp[0], wb = wp[1];
#pragma unroll
                for (int kk = 0; kk < 4; kk++) { w[r][kk] = wa[kk]; w[r][4 + kk] = wb[kk]; }
            }
#pragma unroll
            for (int kk = 0; kk < 8; kk++) {
                float xv = xs[b * 257 + k8 * 8 + kk];
#pragma unroll
                for (int r = 0; r < 4; r++) acc[r] += xv * w[r][kk];
            }
        }
        __syncthreads();
    }
    float* orow = out + ((size_t)(t * 32 + b)) * 512;
#pragma unroll
    for (int r = 0; r < 4; r++) orow[j0 + jj * 4 + r] = tanhf(acc[r]);
}

// ---------------------------------------------------------------------------
extern "C" void kernel_launch(void* const* d_in, const int* in_sizes, int n_in,
                              void* d_out, int out_size, void* d_ws, size_t ws_size,
                              hipStream_t stream) {
    const int* tokens   = (const int*)d_in[0];
    const float* enc    = (const float*)d_in[1];
    const float* hidden = (const float*)d_in[2];
    const float* cells  = (const float*)d_in[3];
    const unsigned char* mask = (const unsigned char*)d_in[4];
    const float* embed  = (const float*)d_in[5];
    const float* W_ih   = (const float*)d_in[6];
    const float* W_hh   = (const float*)d_in[7];
    const float* b_ih   = (const float*)d_in[8];
    const float* b_hh   = (const float*)d_in[9];
    const float* W_in   = (const float*)d_in[10];
    const float* b_in   = (const float*)d_in[11];
    const float* W_out  = (const float*)d_in[12];
    const float* b_out  = (const float*)d_in[13];
    float* out = (float*)d_out;

    float* ws = (float*)d_ws;
    float* gih0 = ws;                              // 4,194,304
    float* h0s  = ws + 4194304;                    // 32768 (2 parities)
    float* h20s = ws + 4227072;                    // 32768
    float* h1s  = ws + 4259840;                    // 32768
    float* H2   = ws + 4292608;                    // 1,048,576
    // bf16 weights occupy XQ's slot (dead until after the phases):
    u16*   WB16 = (u16*)(ws + 5341184);            // 4 x 1,048,576 u16 = 2,097,152 f-slots
    u16*   wih0b = WB16;
    u16*   whh0b = WB16 + 1048576;
    u16*   wih1b = WB16 + 2097152;
    u16*   whh1b = WB16 + 3145728;
    float* XQ   = ws + 5341184;                    // reused AFTER phases
    float* CTX  = ws + 7438336;                    // 2,097,152
    int*   flag = (int*)(ws + 9535488);

    const float* bih1 = b_ih + G4_;
    const float* bhh1 = b_hh + G4_;

    k_flag<<<1, 256, 0, stream>>>(mask, flag);
    k_init2<<<64, 256, 0, stream>>>(hidden, h0s, h1s);
    k_conv<<<4096, 256, 0, stream>>>(W_ih, W_hh, WB16);
    k_gih0<<<dim3(64, 64), 256, 0, stream>>>(tokens, embed, wih0b, b_ih, b_hh, gih0);

    for (int k = 0; k <= 64; k++) {
        const int r = k & 1, w = r ^ 1;
        k_phase<<<512, 256, 0, stream>>>(k, gih0, whh0b, wih1b, whh1b, bih1, bhh1, cells,
                                         h0s + r * 16384, h0s + w * 16384,
                                         h20s + r * 16384, h20s + w * 16384,
                                         h1s + r * 16384, h1s + w * 16384, H2);
    }

    k_x<<<dim3(32, 64), 256, 0, stream>>>(H2, W_in, b_in, XQ);
    k_att<<<dim3(32, 64), 256, 0, stream>>>(XQ, enc, mask, flag, CTX);
    k_out<<<dim3(16, 64), 256, 0, stream>>>(CTX, H2, W_out, b_out, out);
}

// Round 11
// 1690.638 us; speedup vs baseline: 23.4672x; 1.0828x over previous
//
#include <hip/hip_runtime.h>
#include <math.h>

typedef unsigned short u16;
typedef __attribute__((ext_vector_type(4))) float f4;
typedef __attribute__((ext_vector_type(8))) unsigned short us8;

#define BB 32
#define TT 64
#define DD 512
#define G4_ 2048

__device__ __forceinline__ float sigf(float x) { return 1.0f / (1.0f + expf(-x)); }
__device__ __forceinline__ float bf2f(u16 u) {
    union { unsigned int i; float f; } v; v.i = ((unsigned int)u) << 16; return v.f;
}
__device__ __forceinline__ u16 f2bf(float f) {
    union { float f; unsigned int i; } v; v.f = f;
    unsigned int r = v.i + 0x7fffu + ((v.i >> 16) & 1u);
    return (u16)(r >> 16);
}

// ---------------------------------------------------------------------------
// mask dtype classifier: 0=u8(bool), 1=i32, 2=bf16, 3=f32. Deterministic.
// ---------------------------------------------------------------------------
__global__ void k_flag(const unsigned char* __restrict__ m, int* __restrict__ flag) {
    int tid = threadIdx.x;
    int badbyte = 0, nonz_off = 0, evenu16_nz = 0;
    for (int i = tid * 16; i < tid * 16 + 16; i++) {
        unsigned char c = m[i];
        if (c > 1) badbyte = 1;
        if ((i & 3) != 0 && c != 0) nonz_off = 1;
    }
    const u16* mu = (const u16*)m;
    for (int i = tid * 8; i < tid * 8 + 8; i++) {
        if ((i & 1) == 0 && mu[i] != 0) evenu16_nz = 1;
    }
    __shared__ int s_bad, s_noff, s_env;
    if (tid == 0) { s_bad = 0; s_noff = 0; s_env = 0; }
    __syncthreads();
    if (badbyte) atomicOr(&s_bad, 1);
    if (nonz_off) atomicOr(&s_noff, 1);
    if (evenu16_nz) atomicOr(&s_env, 1);
    __syncthreads();
    if (tid == 0) {
        int f;
        if (s_bad) f = s_env ? 2 : 3;
        else       f = s_noff ? 0 : 1;
        *flag = f;
    }
}

// ---------------------------------------------------------------------------
// init: copy initial h-states into both parity buffers.
// ---------------------------------------------------------------------------
__global__ void __launch_bounds__(256) k_init2(const float* __restrict__ hid,
                                               float* __restrict__ h0s,
                                               float* __restrict__ h1s) {
    int i = blockIdx.x * 256 + threadIdx.x;   // 0 .. 16383
    float v0 = hid[i], v1 = hid[16384 + i];
    h0s[i] = v0; h0s[16384 + i] = v0;
    h1s[i] = v1; h1s[16384 + i] = v1;
}

// ---------------------------------------------------------------------------
// convert weights to bf16 (RNE):
//   e in [0, 4194304)        : recurrent [wih0|whh0|wih1|whh1] -> dstR[e]
//   e in [4194304, 4718592)  : W_in  (1024x512)                -> dstIn
//   e in [4718592, 5505024)  : W_out (512x1536)                -> dstOut
// grid 5376 x 256, 4 elems/thread.
// ---------------------------------------------------------------------------
__global__ void __launch_bounds__(256) k_conv(const float* __restrict__ Wih,
                                              const float* __restrict__ Whh,
                                              const float* __restrict__ Win,
                                              const float* __restrict__ Wout,
                                              u16* __restrict__ dstR,
                                              u16* __restrict__ dstIn,
                                              u16* __restrict__ dstOut) {
    size_t e = ((size_t)blockIdx.x * 256 + threadIdx.x) * 4;
    if (e < 4194304) {
        int m = (int)(e >> 20);
        size_t off = e & 1048575;
        const float* src = (m == 0) ? Wih
                         : (m == 1) ? Whh
                         : (m == 2) ? (Wih + 1048576)
                                    : (Whh + 1048576);
        f4 v = *(const f4*)&src[off];
        dstR[e + 0] = f2bf(v[0]); dstR[e + 1] = f2bf(v[1]);
        dstR[e + 2] = f2bf(v[2]); dstR[e + 3] = f2bf(v[3]);
    } else if (e < 4718592) {
        size_t off = e - 4194304;
        f4 v = *(const f4*)&Win[off];
        dstIn[off + 0] = f2bf(v[0]); dstIn[off + 1] = f2bf(v[1]);
        dstIn[off + 2] = f2bf(v[2]); dstIn[off + 3] = f2bf(v[3]);
    } else {
        size_t off = e - 4718592;
        f4 v = *(const f4*)&Wout[off];
        dstOut[off + 0] = f2bf(v[0]); dstOut[off + 1] = f2bf(v[1]);
        dstOut[off + 2] = f2bf(v[2]); dstOut[off + 3] = f2bf(v[3]);
    }
}

// ---------------------------------------------------------------------------
// gih0[t][b][j] = b_ih0[j] + b_hh0[j] + sum_k embed[tok[b,t],k] * W_ih0[j,k]
// W_ih0 in bf16. grid (64 dtiles, 64 t), 256 thr.
// ---------------------------------------------------------------------------
__global__ void __launch_bounds__(256) k_gih0(const int* __restrict__ tokens,
                                              const float* __restrict__ embed,
                                              const u16* __restrict__ Wih0b,
                                              const float* __restrict__ bih,
                                              const float* __restrict__ bhh,
                                              float* __restrict__ gih0) {
    const int tid = threadIdx.x;
    const int d0 = blockIdx.x * 8;
    const int t = blockIdx.y;
    const int b = tid & 31, dd = tid >> 5;
    const int d = d0 + dd;
    __shared__ float xs[32 * 257];
    __shared__ int toks[32];
    if (tid < 32) toks[tid] = tokens[tid * TT + t];
    float acc[4];
#pragma unroll
    for (int g = 0; g < 4; g++) { int j = g * 512 + d; acc[g] = bih[j] + bhh[j]; }
    __syncthreads();
    for (int c = 0; c < 2; c++) {
        for (int idx = tid; idx < 32 * 64; idx += 256) {
            int b2 = idx >> 6, k4 = idx & 63;
            f4 v = *(const f4*)&embed[(size_t)toks[b2] * 512 + c * 256 + k4 * 4];
            float* dst = &xs[b2 * 257 + k4 * 4];
            dst[0] = v[0]; dst[1] = v[1]; dst[2] = v[2]; dst[3] = v[3];
        }
        __syncthreads();
        for (int k8 = 0; k8 < 32; k8++) {
            float w[4][8];
#pragma unroll
            for (int g = 0; g < 4; g++) {
                us8 wv = *(const us8*)&Wih0b[(size_t)(g * 512 + d) * 512 + c * 256 + k8 * 8];
#pragma unroll
                for (int kk = 0; kk < 8; kk++) w[g][kk] = bf2f(wv[kk]);
            }
#pragma unroll
            for (int kk = 0; kk < 8; kk++) {
                float xv = xs[b * 257 + k8 * 8 + kk];
#pragma unroll
                for (int g = 0; g < 4; g++) acc[g] += xv * w[g][kk];
            }
        }
        __syncthreads();
    }
    float* grow = gih0 + ((size_t)(t * 32 + b)) * 2048;
#pragma unroll
    for (int g = 0; g < 4; g++) grow[g * 512 + d] = acc[g];
}

// ---------------------------------------------------------------------------
// Fused phase kernel (launched 65x; stream order = the grid sync).
// blocks [0,256):  stepA(t=k)   (k<64): gates = gih0[k] + h0 @ Whh0^T
// blocks [256,512): stepB(t=k-1)(k>=1): gates = h20@Wih1^T + h1@Whh1^T
// Weights bf16; h-state, biases, gates f32.
// ---------------------------------------------------------------------------
__global__ void __launch_bounds__(256) k_phase(
    const int k,
    const float* __restrict__ gih0,
    const u16* __restrict__ Whh0b,
    const u16* __restrict__ Wih1b,
    const u16* __restrict__ Whh1b,
    const float* __restrict__ bih1,
    const float* __restrict__ bhh1,
    const float* __restrict__ cells,
    const float* __restrict__ h0r, float* __restrict__ h0w,
    const float* __restrict__ h20r, float* __restrict__ h20w,
    const float* __restrict__ h1r, float* __restrict__ h1w,
    float* __restrict__ H2)
{
    const int tid = threadIdx.x;
    const int b = tid & 31, u = tid >> 5;       // u = row m, 0..7
    __shared__ float xs[32][257];
    __shared__ float gbuf[8][33];

    if (blockIdx.x < 256) {                     // ======== stepA (t = k)
        if (k >= 64) return;
        const int d0 = blockIdx.x * 2;
        const int j = (u >> 1) * 512 + d0 + (u & 1);
        float a = gih0[(size_t)k * 65536 + b * 2048 + j];
        const u16* WA = Whh0b + (size_t)j * 512;
        for (int c = 0; c < 2; c++) {
            __syncthreads();
            for (int i = tid; i < 2048; i += 256) {
                int b2 = i >> 6, k4 = i & 63;
                *(f4*)&xs[b2][k4 * 4] = *(const f4*)&h0r[b2 * 512 + c * 256 + k4 * 4];
            }
            __syncthreads();
            const u16* wp = WA + c * 256;
            for (int k8 = 0; k8 < 32; k8++) {
                us8 wv = *(const us8*)&wp[k8 * 8];
                f4 x0 = *(const f4*)&xs[b][k8 * 8];
                f4 x1 = *(const f4*)&xs[b][k8 * 8 + 4];
                a += x0[0] * bf2f(wv[0]); a += x0[1] * bf2f(wv[1]);
                a += x0[2] * bf2f(wv[2]); a += x0[3] * bf2f(wv[3]);
                a += x1[0] * bf2f(wv[4]); a += x1[1] * bf2f(wv[5]);
                a += x1[2] * bf2f(wv[6]); a += x1[3] * bf2f(wv[7]);
            }
        }
        gbuf[u][b] = a;
        __syncthreads();
        if (tid < 64) {
            int bb = tid & 31, dd = tid >> 5;   // dd 0..1
            float gi = gbuf[0 + dd][bb], gf = gbuf[2 + dd][bb];
            float gg = gbuf[4 + dd][bb], go = gbuf[6 + dd][bb];
            float cell = cells[bb * 512 + d0 + dd];
            float c2 = sigf(gf) * cell + sigf(gi) * tanhf(gg);
            float h2 = sigf(go) * tanhf(c2);
            h0w[bb * 512 + d0 + dd] = c2;       // faithful bug: carry = cell
            h20w[bb * 512 + d0 + dd] = h2;
        }
    } else {                                    // ======== stepB (t = k-1)
        if (k < 1) return;
        const int d0 = (blockIdx.x - 256) * 2;
        const int j = (u >> 1) * 512 + d0 + (u & 1);
        float a = bih1[j] + bhh1[j];
        const u16* WI = Wih1b + (size_t)j * 512;
        const u16* WH = Whh1b + (size_t)j * 512;
        for (int c = 0; c < 4; c++) {
            const float* srcb = (c < 2) ? h20r : h1r;
            const int off = (c & 1) * 256;
            const u16* wp = ((c < 2) ? WI : WH) + off;
            __syncthreads();
            for (int i = tid; i < 2048; i += 256) {
                int b2 = i >> 6, k4 = i & 63;
                *(f4*)&xs[b2][k4 * 4] = *(const f4*)&srcb[b2 * 512 + off + k4 * 4];
            }
            __syncthreads();
            for (int k8 = 0; k8 < 32; k8++) {
                us8 wv = *(const us8*)&wp[k8 * 8];
                f4 x0 = *(const f4*)&xs[b][k8 * 8];
                f4 x1 = *(const f4*)&xs[b][k8 * 8 + 4];
                a += x0[0] * bf2f(wv[0]); a += x0[1] * bf2f(wv[1]);
                a += x0[2] * bf2f(wv[2]); a += x0[3] * bf2f(wv[3]);
                a += x1[0] * bf2f(wv[4]); a += x1[1] * bf2f(wv[5]);
                a += x1[2] * bf2f(wv[6]); a += x1[3] * bf2f(wv[7]);
            }
        }
        gbuf[u][b] = a;
        __syncthreads();
        if (tid < 64) {
            int bb = tid & 31, dd = tid >> 5;   // dd 0..1
            float gi = gbuf[0 + dd][bb], gf = gbuf[2 + dd][bb];
            float gg = gbuf[4 + dd][bb], go = gbuf[6 + dd][bb];
            float cell = cells[16384 + bb * 512 + d0 + dd];
            float c2 = sigf(gf) * cell + sigf(gi) * tanhf(gg);
            float h2 = sigf(go) * tanhf(c2);
            h1w[bb * 512 + d0 + dd] = c2;       // faithful bug
            H2[(size_t)(k - 1) * 16384 + bb * 512 + d0 + dd] = h2;
        }
    }
}

// ---------------------------------------------------------------------------
// XQ[t,b,:] = H2[t,b,:] @ W_in^T + b_in   (W_in bf16)
// ---------------------------------------------------------------------------
__global__ void __launch_bounds__(256) k_x(const float* __restrict__ H2,
                                           const u16* __restrict__ Winb,
                                           const float* __restrict__ bin,
                                           float* __restrict__ XQ) {
    const int tid = threadIdx.x;
    const int j0 = blockIdx.x * 32;
    const int t = blockIdx.y;
    const int b = tid & 31, jj = tid >> 5;
    __shared__ float xs[32 * 257];
    float acc[4];
#pragma unroll
    for (int r = 0; r < 4; r++) acc[r] = bin[j0 + jj * 4 + r];
    const float* H2t = H2 + (size_t)t * 32 * 512;
    for (int c = 0; c < 2; c++) {
        for (int idx = tid; idx < 32 * 64; idx += 256) {
            int b2 = idx >> 6, k4 = idx & 63;
            f4 v = *(const f4*)&H2t[b2 * 512 + c * 256 + k4 * 4];
            float* dst = &xs[b2 * 257 + k4 * 4];
            dst[0] = v[0]; dst[1] = v[1]; dst[2] = v[2]; dst[3] = v[3];
        }
        __syncthreads();
        for (int k8 = 0; k8 < 32; k8++) {
            float w[4][8];
#pragma unroll
            for (int r = 0; r < 4; r++) {
                us8 wv = *(const us8*)&Winb[(size_t)(j0 + jj * 4 + r) * 512 + c * 256 + k8 * 8];
#pragma unroll
                for (int kk = 0; kk < 8; kk++) w[r][kk] = bf2f(wv[kk]);
            }
#pragma unroll
            for (int kk = 0; kk < 8; kk++) {
                float xv = xs[b * 257 + k8 * 8 + kk];
#pragma unroll
                for (int r = 0; r < 4; r++) acc[r] += xv * w[r][kk];
            }
        }
        __syncthreads();
    }
    float* xrow = XQ + ((size_t)(t * 32 + b)) * 1024;
#pragma unroll
    for (int r = 0; r < 4; r++) xrow[j0 + jj * 4 + r] = acc[r];
}

// ---------------------------------------------------------------------------
// attention per (t,b): e = enc . xq, masked softmax, ctx = attn . enc
// ---------------------------------------------------------------------------
__global__ void __launch_bounds__(256) k_att(const float* __restrict__ XQ,
                                             const float* __restrict__ enc,
                                             const unsigned char* __restrict__ mask,
                                             const int* __restrict__ flag,
                                             float* __restrict__ CTX) {
    const int tid = threadIdx.x;
    const int b = blockIdx.x, t = blockIdx.y;
    __shared__ float xq[1024];
    __shared__ float ered[256];
    __shared__ float attn[128];
    __shared__ float red2[8];
    {
        f4 v = *(const f4*)&XQ[((size_t)(t * 32 + b)) * 1024 + tid * 4];
        float* dst = &xq[tid * 4];
        dst[0] = v[0]; dst[1] = v[1]; dst[2] = v[2]; dst[3] = v[3];
    }
    __syncthreads();
    const int s = tid >> 1, hh = tid & 1;
    float part = 0.f;
    const float* erow = enc + ((size_t)(b * 128 + s)) * 1024 + hh * 512;
    const float* xqh = &xq[hh * 512];
    for (int k4 = 0; k4 < 128; k4++) {
        f4 u = *(const f4*)&erow[k4 * 4];
#pragma unroll
        for (int kk = 0; kk < 4; kk++) part += u[kk] * xqh[k4 * 4 + kk];
    }
    ered[tid] = part;
    __syncthreads();
    float e = -INFINITY;
    if (tid < 128) {
        e = ered[2 * tid] + ered[2 * tid + 1];
        int f = *flag;
        bool msk;
        if (f == 0)      msk = mask[b * 128 + tid] != 0;
        else if (f == 1) msk = ((const int*)mask)[b * 128 + tid] != 0;
        else if (f == 2) msk = ((const u16*)mask)[b * 128 + tid] != 0;
        else             msk = ((const unsigned int*)mask)[b * 128 + tid] != 0;
        if (msk) e = -1e9f;
    }
    float v = e;
#pragma unroll
    for (int off = 32; off >= 1; off >>= 1) v = fmaxf(v, __shfl_xor(v, off));
    const int wave = tid >> 6;
    if ((tid & 63) == 0) red2[wave] = v;
    __syncthreads();
    float m = fmaxf(fmaxf(red2[0], red2[1]), fmaxf(red2[2], red2[3]));
    float p = (tid < 128) ? expf(e - m) : 0.f;
    float su = p;
#pragma unroll
    for (int off = 32; off >= 1; off >>= 1) su += __shfl_xor(su, off);
    __syncthreads();
    if ((tid & 63) == 0) red2[4 + wave] = su;
    __syncthreads();
    float S = (red2[4] + red2[5]) + (red2[6] + red2[7]);
    if (tid < 128) attn[tid] = p / S;
    __syncthreads();
    float c0 = 0, c1 = 0, c2 = 0, c3 = 0;
    const float* eb = enc + ((size_t)b * 128) * 1024 + tid * 4;
    for (int s2 = 0; s2 < 128; s2++) {
        float a = attn[s2];
        f4 u = *(const f4*)&eb[(size_t)s2 * 1024];
        c0 += a * u[0]; c1 += a * u[1]; c2 += a * u[2]; c3 += a * u[3];
    }
    float* crow = CTX + ((size_t)(t * 32 + b)) * 1024 + tid * 4;
    crow[0] = c0; crow[1] = c1; crow[2] = c2; crow[3] = c3;
}

// ---------------------------------------------------------------------------
// out[t,b,:] = tanh([ctx, s] @ W_out^T + b_out)  -> f32 d_out
// 2 time-steps per block: grid (16 j-tiles, 32 t-pairs). W_out bf16; each
// weight register-load feeds both t's FMAs. Per-(t,thread) summation order
// identical to the single-t kernel.
// ---------------------------------------------------------------------------
__global__ void __launch_bounds__(256) k_out2(const float* __restrict__ CTX,
                                              const float* __restrict__ H2,
                                              const u16* __restrict__ Woutb,
                                              const float* __restrict__ bout,
                                              float* __restrict__ out) {
    const int tid = threadIdx.x;
    const int j0 = blockIdx.x * 32;
    const int t0 = blockIdx.y * 2;
    const int b = tid & 31, jj = tid >> 5;
    __shared__ float xs[2][32][257];
    float acc[2][4];
#pragma unroll
    for (int tg = 0; tg < 2; tg++)
#pragma unroll
        for (int r = 0; r < 4; r++) acc[tg][r] = bout[j0 + jj * 4 + r];
    for (int c = 0; c < 6; c++) {
        for (int idx = tid; idx < 2 * 32 * 64; idx += 256) {
            int tg = idx >> 11;
            int rem = idx & 2047;
            int b2 = rem >> 6, k4 = rem & 63;
            int t = t0 + tg;
            const float* src = (c < 4) ? &CTX[(size_t)(t * 32 + b2) * 1024 + c * 256]
                                       : &H2[(size_t)t * 16384 + b2 * 512 + (c - 4) * 256];
            f4 v = *(const f4*)&src[k4 * 4];
            float* dst = &xs[tg][b2][k4 * 4];
            dst[0] = v[0]; dst[1] = v[1]; dst[2] = v[2]; dst[3] = v[3];
        }
        __syncthreads();
        for (int k8 = 0; k8 < 32; k8++) {
            float w[4][8];
#pragma unroll
            for (int r = 0; r < 4; r++) {
                us8 wv = *(const us8*)&Woutb[(size_t)(j0 + jj * 4 + r) * 1536 + c * 256 + k8 * 8];
#pragma unroll
                for (int kk = 0; kk < 8; kk++) w[r][kk] = bf2f(wv[kk]);
            }
#pragma unroll
            for (int tg = 0; tg < 2; tg++) {
#pragma unroll
                for (int kk = 0; kk < 8; kk++) {
                    float xv = xs[tg][b][k8 * 8 + kk];
#pragma unroll
                    for (int r = 0; r < 4; r++) acc[tg][r] += xv * w[r][kk];
                }
            }
        }
        __syncthreads();
    }
#pragma unroll
    for (int tg = 0; tg < 2; tg++) {
        float* orow = out + ((size_t)((t0 + tg) * 32 + b)) * 512;
#pragma unroll
        for (int r = 0; r < 4; r++) orow[j0 + jj * 4 + r] = tanhf(acc[tg][r]);
    }
}

// ---------------------------------------------------------------------------
extern "C" void kernel_launch(void* const* d_in, const int* in_sizes, int n_in,
                              void* d_out, int out_size, void* d_ws, size_t ws_size,
                              hipStream_t stream) {
    const int* tokens   = (const int*)d_in[0];
    const float* enc    = (const float*)d_in[1];
    const float* hidden = (const float*)d_in[2];
    const float* cells  = (const float*)d_in[3];
    const unsigned char* mask = (const unsigned char*)d_in[4];
    const float* embed  = (const float*)d_in[5];
    const float* W_ih   = (const float*)d_in[6];
    const float* W_hh   = (const float*)d_in[7];
    const float* b_ih   = (const float*)d_in[8];
    const float* b_hh   = (const float*)d_in[9];
    const float* W_in   = (const float*)d_in[10];
    const float* b_in   = (const float*)d_in[11];
    const float* W_out  = (const float*)d_in[12];
    const float* b_out  = (const float*)d_in[13];
    float* out = (float*)d_out;

    float* ws = (float*)d_ws;
    // Phase-time layout:
    float* gih0 = ws;                              // [0, 4194304) — dead after phases
    float* h0s  = ws + 4194304;                    // 32768 (2 parities)
    float* h20s = ws + 4227072;                    // 32768
    float* h1s  = ws + 4259840;                    // 32768
    float* H2   = ws + 4292608;                    // 1,048,576
    u16*   WB16 = (u16*)(ws + 5341184);            // recurrent bf16: 4 x 1048576 u16
    u16*   wih0b = WB16;
    u16*   whh0b = WB16 + 1048576;
    u16*   wih1b = WB16 + 2097152;
    u16*   whh1b = WB16 + 3145728;
    u16*   winb  = (u16*)(ws + 7438336);           // 524288 u16  = [7438336, 7700480)
    u16*   woutb = (u16*)(ws + 7700480);           // 786432 u16  = [7700480, 8093696)
    // Tail-time layout (gih0 region reused):
    float* XQ   = ws;                              // [0, 2097152)
    float* CTX  = ws + 2097152;                    // [2097152, 4194304)
    int*   flag = (int*)(ws + 9535488);

    const float* bih1 = b_ih + G4_;
    const float* bhh1 = b_hh + G4_;

    k_flag<<<1, 256, 0, stream>>>(mask, flag);
    k_init2<<<64, 256, 0, stream>>>(hidden, h0s, h1s);
    k_conv<<<5376, 256, 0, stream>>>(W_ih, W_hh, W_in, W_out, WB16, winb, woutb);
    k_gih0<<<dim3(64, 64), 256, 0, stream>>>(tokens, embed, wih0b, b_ih, b_hh, gih0);

    for (int k = 0; k <= 64; k++) {
        const int r = k & 1, w = r ^ 1;
        k_phase<<<512, 256, 0, stream>>>(k, gih0, whh0b, wih1b, whh1b, bih1, bhh1, cells,
                                         h0s + r * 16384, h0s + w * 16384,
                                         h20s + r * 16384, h20s + w * 16384,
                                         h1s + r * 16384, h1s + w * 16384, H2);
    }

    k_x<<<dim3(32, 64), 256, 0, stream>>>(H2, winb, b_in, XQ);
    k_att<<<dim3(32, 64), 256, 0, stream>>>(XQ, enc, mask, flag, CTX);
    k_out2<<<dim3(16, 32), 256, 0, stream>>>(CTX, H2, woutb, b_out, out);
}